// Round 1
// baseline (1345.721 us; speedup 1.0000x reference)
//
#include <hip/hip_runtime.h>
#include <math.h>

#define DDIM 100   // embed dim
#define BK   100   // K-chunk staged in LDS (K is always 100 or 300)

// ---------------------------------------------------------------- utilities

__device__ __forceinline__ float wave_sum64(float v) {
#pragma unroll
  for (int o = 32; o > 0; o >>= 1) v += __shfl_xor(v, o, 64);
  return v;
}

__device__ __forceinline__ float sigm(float x) { return 1.f / (1.f + expf(-x)); }

// ---------------------------------------------------------------- elementwise

__global__ void k_transpose(const float* __restrict__ w, float* __restrict__ wT, int d) {
  int i = blockIdx.x * 256 + threadIdx.x;
  if (i < d * d) { int r = i / d, c = i - r * d; wT[(size_t)c * d + r] = w[i]; }
}

// h0 = emb[x-1], agg = 0
__global__ void k_gather4(const int* __restrict__ x, const float* __restrict__ emb,
                          float4* __restrict__ h0, float4* __restrict__ agg, int n) {
  int i = blockIdx.x * 256 + threadIdx.x;
  if (i < n * 25) {
    int node = i / 25, c = i - node * 25;
    h0[i] = *(const float4*)(emb + (size_t)(x[node] - 1) * DDIM + 4 * c);
    agg[i] = make_float4(0.f, 0.f, 0.f, 0.f);
  }
}

// agg[dst] += m[src]   (low contention: ~2 edges/node avg)
__global__ void k_scatter(const int* __restrict__ ei, const float* __restrict__ m,
                          float* __restrict__ agg, int E) {
  int i = blockIdx.x * 256 + threadIdx.x;
  if (i < E * 25) {
    int e = i / 25, c = i - e * 25;
    int s = ei[e], d = ei[E + e];
    float4 v = *(const float4*)(m + (size_t)s * DDIM + 4 * c);
    float* ap = agg + (size_t)d * DDIM + 4 * c;
    atomicAdd(ap + 0, v.x); atomicAdd(ap + 1, v.y);
    atomicAdd(ap + 2, v.z); atomicAdd(ap + 3, v.w);
  }
}

// gi holds [i_r+h_r | i_z+h_z | i_n] (300/row), hn holds h_n (100/row)
__global__ void k_gru(const float* __restrict__ gi, const float* __restrict__ hn,
                      const float* __restrict__ h0, float* __restrict__ xh, int n) {
  int i = blockIdx.x * 256 + threadIdx.x;
  if (i < n * DDIM) {
    int node = i / DDIM, d = i - node * DDIM;
    const float* g = gi + (size_t)node * 300;
    float r = sigm(g[d]);
    float z = sigm(g[100 + d]);
    float nn = tanhf(g[200 + d] + r * hn[i]);
    float v = (1.f - z) * nn + z * h0[i];
    xh[i] = v > 0.f ? v : 0.f;
  }
}

__global__ void k_last(const int* __restrict__ batch, int* __restrict__ last_idx, int n) {
  int i = blockIdx.x * 256 + threadIdx.x;
  if (i < n) {
    if (i == n - 1 || batch[i + 1] != batch[i]) last_idx[batch[i]] = i;
  }
}

__global__ void k_vn(const float* __restrict__ xh, const int* __restrict__ last_idx,
                     float4* __restrict__ vn, int b) {
  int i = blockIdx.x * 256 + threadIdx.x;
  if (i < b * 25) {
    int s = i / 25, c = i - s * 25;
    vn[i] = *(const float4*)(xh + (size_t)last_idx[s] * DDIM + 4 * c);
  }
}

// one wave per session: online softmax pooling (S_s), gated pooling (S_g), v_n
// writes Scat[sid] = [S_s | S_g | v_n]  (300 floats)
__global__ __launch_bounds__(256) void k_session(
    const float* __restrict__ xh, const float* __restrict__ t2,
    const float* __restrict__ vn, const float* __restrict__ t3v,
    const float* __restrict__ q_w, const float* __restrict__ q_b,
    const int* __restrict__ last_idx, float* __restrict__ Scat, int B) {
  int sid = blockIdx.x * 4 + (threadIdx.x >> 6);
  if (sid >= B) return;
  int lane = threadIdx.x & 63;
  bool hi = lane < (DDIM - 64);  // 36
  int start = (sid == 0) ? 0 : last_idx[sid - 1] + 1;
  int end = last_idx[sid];  // inclusive, session non-empty

  float v0 = vn[(size_t)sid * DDIM + lane];
  float v1 = hi ? vn[(size_t)sid * DDIM + 64 + lane] : 0.f;
  float t30 = t3v[(size_t)sid * DDIM + lane];
  float t31 = hi ? t3v[(size_t)sid * DDIM + 64 + lane] : 0.f;
  float q0 = q_w[lane];
  float q1 = hi ? q_w[64 + lane] : 0.f;
  float qb = q_b[0];

  // pass 1: session max of logits
  float mx = -INFINITY;
  for (int i = start; i <= end; ++i) {
    float x0 = xh[(size_t)i * DDIM + lane];
    float x1 = hi ? xh[(size_t)i * DDIM + 64 + lane] : 0.f;
    float l = wave_sum64(x0 * v0 + x1 * v1);
    mx = fmaxf(mx, l);
  }
  // pass 2: denom + unnormalized S_s, and S_g
  float denom = 0.f, ss0 = 0.f, ss1 = 0.f, sg0 = 0.f, sg1 = 0.f;
  for (int i = start; i <= end; ++i) {
    float x0 = xh[(size_t)i * DDIM + lane];
    float x1 = hi ? xh[(size_t)i * DDIM + 64 + lane] : 0.f;
    float l = wave_sum64(x0 * v0 + x1 * v1);   // identical on all lanes
    float p = expf(l - mx);
    denom += p;                                 // identical on all lanes
    float g0 = sigm(t2[(size_t)i * DDIM + lane] + t30);
    float g1 = hi ? sigm(t2[(size_t)i * DDIM + 64 + lane] + t31) : 0.f;
    float alpha = wave_sum64(q0 * g0 + q1 * g1) + qb;
    ss0 += p * x0; ss1 += p * x1;
    sg0 += alpha * x0; sg1 += alpha * x1;
  }
  float inv = 1.f / denom;
  float* Sc = Scat + (size_t)sid * 300;
  Sc[lane] = ss0 * inv;       if (hi) Sc[64 + lane] = ss1 * inv;
  Sc[100 + lane] = sg0;       if (hi) Sc[164 + lane] = sg1;
  Sc[200 + lane] = v0;        if (hi) Sc[264 + lane] = v1;
}

// ---------------------------------------------------------------- GEMM  C = A @ B^T
// A [M,KTOT] row-major, Bm [Nout,KTOT] row-major -> C[i][j] = dot(A_i, B_j)
// Block tile 128x64, 256 threads, per-thread 8x4; k vectorized by float4.
// LDS layout: k4-major float4 arrays with XOR swizzle (r ^ (k4&7)) ->
//   A-reads conflict-free, B-reads 2-way (free), staging writes ~3-way.
// MODE: 0 = C=dot, 1 = C=dot+bias, 2 = gh-special: cols<200: C += dot+bias
//       (accumulate into gi), cols>=200: C2[row*100+col-200] = dot+bias.
template <int KTOT, int MODE>
__global__ __launch_bounds__(256, 2) void gemm_abt(
    const float* __restrict__ A, const float* __restrict__ Bm,
    const float* __restrict__ bias, float* __restrict__ C,
    float* __restrict__ C2, int M, int Nout) {
  __shared__ float4 As4[25 * 128];  // 51.2 KB
  __shared__ float4 Bs4[25 * 64];   // 25.6 KB
  const int m0 = blockIdx.y * 128;
  const int n0 = blockIdx.x * 64;
  const int t = threadIdx.x;
  const int tx = t & 15;   // col group
  const int ty = t >> 4;   // row group (0..15)
  float acc[8][4] = {};

  for (int kt = 0; kt < KTOT; kt += BK) {
    // stage A tile (128 rows x 25 float4)
    for (int idx = t; idx < 128 * 25; idx += 256) {
      int r = idx / 25, k4 = idx - r * 25;
      int ar = m0 + r; if (ar >= M) ar = M - 1;
      float4 v = *(const float4*)(A + (size_t)ar * KTOT + kt + 4 * k4);
      As4[k4 * 128 + (r ^ (k4 & 7))] = v;
    }
    // stage B tile (64 rows x 25 float4), zero-fill past Nout
    for (int idx = t; idx < 64 * 25; idx += 256) {
      int r = idx / 25, k4 = idx - r * 25;
      int br = n0 + r;
      float4 v = make_float4(0.f, 0.f, 0.f, 0.f);
      if (br < Nout) v = *(const float4*)(Bm + (size_t)br * KTOT + kt + 4 * k4);
      Bs4[k4 * 64 + (r ^ (k4 & 7))] = v;
    }
    __syncthreads();
#pragma unroll 5
    for (int k4 = 0; k4 < 25; ++k4) {
      const int s = k4 & 7;
      float4 av[8], bv[4];
#pragma unroll
      for (int i = 0; i < 8; ++i) av[i] = As4[k4 * 128 + ((ty + 16 * i) ^ s)];
#pragma unroll
      for (int j = 0; j < 4; ++j) bv[j] = Bs4[k4 * 64 + ((tx + 16 * j) ^ s)];
#pragma unroll
      for (int i = 0; i < 8; ++i) {
#pragma unroll
        for (int j = 0; j < 4; ++j) {
          acc[i][j] = fmaf(av[i].x, bv[j].x, acc[i][j]);
          acc[i][j] = fmaf(av[i].y, bv[j].y, acc[i][j]);
          acc[i][j] = fmaf(av[i].z, bv[j].z, acc[i][j]);
          acc[i][j] = fmaf(av[i].w, bv[j].w, acc[i][j]);
        }
      }
    }
    __syncthreads();
  }

  // epilogue: row = m0 + ty + 16i, col = n0 + tx + 16j (scalar, coalesced in tx)
#pragma unroll
  for (int i = 0; i < 8; ++i) {
    int row = m0 + ty + 16 * i;
    if (row >= M) continue;
#pragma unroll
    for (int j = 0; j < 4; ++j) {
      int col = n0 + tx + 16 * j;
      if (col >= Nout) continue;
      float v = acc[i][j];
      if (MODE >= 1) v += bias[col];
      if (MODE == 2) {
        if (col < 200) {
          float* p = C + (size_t)row * 300 + col;
          *p = *p + v;                       // accumulate h_r,h_z into gi
        } else {
          C2[(size_t)row * DDIM + (col - 200)] = v;  // h_n
        }
      } else {
        C[(size_t)row * Nout + col] = v;
      }
    }
  }
}

// ---------------------------------------------------------------- launcher

extern "C" void kernel_launch(void* const* d_in, const int* in_sizes, int n_in,
                              void* d_out, int out_size, void* d_ws, size_t ws_size,
                              hipStream_t stream) {
  const int*   x      = (const int*)d_in[0];
  const int*   ei     = (const int*)d_in[1];
  const int*   batch  = (const int*)d_in[2];
  // d_in[3] = num_sessions (device scalar) -- derived from out_size instead
  const float* emb    = (const float*)d_in[4];
  const float* conv_w = (const float*)d_in[5];
  const float* w_ih   = (const float*)d_in[6];
  const float* w_hh   = (const float*)d_in[7];
  const float* b_ih   = (const float*)d_in[8];
  const float* b_hh   = (const float*)d_in[9];
  const float* q_w    = (const float*)d_in[10];
  const float* q_b    = (const float*)d_in[11];
  const float* w2     = (const float*)d_in[12];
  const float* b2     = (const float*)d_in[13];
  const float* w3     = (const float*)d_in[14];
  const float* b3     = (const float*)d_in[15];
  const float* w4     = (const float*)d_in[16];
  const float* b4     = (const float*)d_in[17];

  const int N = in_sizes[0];           // 49152
  const int E = in_sizes[1] / 2;       // 98304
  const int NNODE = in_sizes[4] / DDIM;// 50000
  const int B = out_size / NNODE;      // 4096

  // workspace arena (floats); peak ~148 MB
  size_t ND = (size_t)N * DDIM;
  float* ws    = (float*)d_ws;
  float* h0    = ws;                 // [N,100]
  float* m_    = ws + ND;            // [N,100]  -> reused as xh
  float* agg   = ws + 2 * ND;        // [N,100]  -> reused as t2
  float* gi    = ws + 3 * ND;        // [N,300]
  float* hn    = ws + 6 * ND;        // [N,100]
  float* aux   = ws + 7 * ND;
  float* cwT   = aux;                          // [100,100]
  float* vn    = cwT + DDIM * DDIM;            // [B,100]
  float* t3v   = vn + (size_t)B * DDIM;        // [B,100]
  float* Scat  = t3v + (size_t)B * DDIM;       // [B,300]
  float* Sm    = Scat + 3 * (size_t)B * DDIM;  // [B,100]
  int*   lastI = (int*)(Sm + (size_t)B * DDIM);// [B]
  float* xh = m_;
  float* t2 = agg;

  dim3 blk(256);
  int gy = (N + 127) / 128;   // 384
  int gyB = (B + 127) / 128;  // 32

  k_transpose<<<(DDIM * DDIM + 255) / 256, blk, 0, stream>>>(conv_w, cwT, DDIM);
  k_gather4<<<(N * 25 + 255) / 256, blk, 0, stream>>>(x, emb, (float4*)h0, (float4*)agg, N);
  // m = h0 @ conv_w  (== h0 @ cwT^T)
  gemm_abt<100, 0><<<dim3(2, gy), blk, 0, stream>>>(h0, cwT, nullptr, m_, nullptr, N, DDIM);
  k_scatter<<<(E * 25 + 255) / 256, blk, 0, stream>>>(ei, m_, agg, E);
  // gi = agg @ w_ih^T + b_ih     [N,300]
  gemm_abt<100, 1><<<dim3(5, gy), blk, 0, stream>>>(agg, w_ih, b_ih, gi, nullptr, N, 300);
  // gh = h0 @ w_hh^T + b_hh ; r,z parts += into gi ; n part -> hn
  gemm_abt<100, 2><<<dim3(5, gy), blk, 0, stream>>>(h0, w_hh, b_hh, gi, hn, N, 300);
  k_gru<<<(N * DDIM + 255) / 256, blk, 0, stream>>>(gi, hn, h0, xh, N);
  k_last<<<(N + 255) / 256, blk, 0, stream>>>(batch, lastI, N);
  k_vn<<<(B * 25 + 255) / 256, blk, 0, stream>>>(xh, lastI, (float4*)vn, B);
  // t2 = xh @ w2^T + b2  [N,100] ; t3v = vn @ w3^T + b3  [B,100]
  gemm_abt<100, 1><<<dim3(2, gy), blk, 0, stream>>>(xh, w2, b2, t2, nullptr, N, DDIM);
  gemm_abt<100, 1><<<dim3(2, gyB), blk, 0, stream>>>(vn, w3, b3, t3v, nullptr, B, DDIM);
  k_session<<<(B + 3) / 4, blk, 0, stream>>>(xh, t2, vn, t3v, q_w, q_b, lastI, Scat, B);
  // S = Scat @ w4^T + b4  [B,100]
  gemm_abt<300, 1><<<dim3(2, gyB), blk, 0, stream>>>(Scat, w4, b4, Sm, nullptr, B, DDIM);
  // y = S @ emb^T  [B, NNODE]  -- dominant GEMM
  gemm_abt<100, 0><<<dim3((NNODE + 63) / 64, gyB), blk, 0, stream>>>(
      Sm, emb, nullptr, (float*)d_out, nullptr, B, NNODE);
}

// Round 2
// 799.371 us; speedup vs baseline: 1.6835x; 1.6835x over previous
//
#include <hip/hip_runtime.h>
#include <math.h>

#define DDIM 100   // embed dim
#define BK   100   // K-chunk staged in LDS (K is always 100 or 300)

using short8 = __attribute__((ext_vector_type(8))) short;
using f32x4  = __attribute__((ext_vector_type(4))) float;

// ---------------------------------------------------------------- utilities

__device__ __forceinline__ float wave_sum64(float v) {
#pragma unroll
  for (int o = 32; o > 0; o >>= 1) v += __shfl_xor(v, o, 64);
  return v;
}

__device__ __forceinline__ float sigm(float x) { return 1.f / (1.f + expf(-x)); }

// ---------------------------------------------------------------- elementwise

__global__ void k_transpose(const float* __restrict__ w, float* __restrict__ wT, int d) {
  int i = blockIdx.x * 256 + threadIdx.x;
  if (i < d * d) { int r = i / d, c = i - r * d; wT[(size_t)c * d + r] = w[i]; }
}

// h0 = emb[x-1], agg = 0
__global__ void k_gather4(const int* __restrict__ x, const float* __restrict__ emb,
                          float4* __restrict__ h0, float4* __restrict__ agg, int n) {
  int i = blockIdx.x * 256 + threadIdx.x;
  if (i < n * 25) {
    int node = i / 25, c = i - node * 25;
    h0[i] = *(const float4*)(emb + (size_t)(x[node] - 1) * DDIM + 4 * c);
    agg[i] = make_float4(0.f, 0.f, 0.f, 0.f);
  }
}

// agg[dst] += m[src]   (low contention: ~2 edges/node avg)
__global__ void k_scatter(const int* __restrict__ ei, const float* __restrict__ m,
                          float* __restrict__ agg, int E) {
  int i = blockIdx.x * 256 + threadIdx.x;
  if (i < E * 25) {
    int e = i / 25, c = i - e * 25;
    int s = ei[e], d = ei[E + e];
    float4 v = *(const float4*)(m + (size_t)s * DDIM + 4 * c);
    float* ap = agg + (size_t)d * DDIM + 4 * c;
    atomicAdd(ap + 0, v.x); atomicAdd(ap + 1, v.y);
    atomicAdd(ap + 2, v.z); atomicAdd(ap + 3, v.w);
  }
}

// gi holds [i_r+h_r | i_z+h_z | i_n] (300/row), hn holds h_n (100/row)
__global__ void k_gru(const float* __restrict__ gi, const float* __restrict__ hn,
                      const float* __restrict__ h0, float* __restrict__ xh, int n) {
  int i = blockIdx.x * 256 + threadIdx.x;
  if (i < n * DDIM) {
    int node = i / DDIM, d = i - node * DDIM;
    const float* g = gi + (size_t)node * 300;
    float r = sigm(g[d]);
    float z = sigm(g[100 + d]);
    float nn = tanhf(g[200 + d] + r * hn[i]);
    float v = (1.f - z) * nn + z * h0[i];
    xh[i] = v > 0.f ? v : 0.f;
  }
}

__global__ void k_last(const int* __restrict__ batch, int* __restrict__ last_idx, int n) {
  int i = blockIdx.x * 256 + threadIdx.x;
  if (i < n) {
    if (i == n - 1 || batch[i + 1] != batch[i]) last_idx[batch[i]] = i;
  }
}

__global__ void k_vn(const float* __restrict__ xh, const int* __restrict__ last_idx,
                     float4* __restrict__ vn, int b) {
  int i = blockIdx.x * 256 + threadIdx.x;
  if (i < b * 25) {
    int s = i / 25, c = i - s * 25;
    vn[i] = *(const float4*)(xh + (size_t)last_idx[s] * DDIM + 4 * c);
  }
}

// one wave per session: softmax pooling (S_s), gated pooling (S_g), v_n
// writes Scat[sid] = [S_s | S_g | v_n]  (300 floats)
__global__ __launch_bounds__(256) void k_session(
    const float* __restrict__ xh, const float* __restrict__ t2,
    const float* __restrict__ vn, const float* __restrict__ t3v,
    const float* __restrict__ q_w, const float* __restrict__ q_b,
    const int* __restrict__ last_idx, float* __restrict__ Scat, int B) {
  int sid = blockIdx.x * 4 + (threadIdx.x >> 6);
  if (sid >= B) return;
  int lane = threadIdx.x & 63;
  bool hi = lane < (DDIM - 64);  // 36
  int start = (sid == 0) ? 0 : last_idx[sid - 1] + 1;
  int end = last_idx[sid];  // inclusive, session non-empty

  float v0 = vn[(size_t)sid * DDIM + lane];
  float v1 = hi ? vn[(size_t)sid * DDIM + 64 + lane] : 0.f;
  float t30 = t3v[(size_t)sid * DDIM + lane];
  float t31 = hi ? t3v[(size_t)sid * DDIM + 64 + lane] : 0.f;
  float q0 = q_w[lane];
  float q1 = hi ? q_w[64 + lane] : 0.f;
  float qb = q_b[0];

  float mx = -INFINITY;
  for (int i = start; i <= end; ++i) {
    float x0 = xh[(size_t)i * DDIM + lane];
    float x1 = hi ? xh[(size_t)i * DDIM + 64 + lane] : 0.f;
    float l = wave_sum64(x0 * v0 + x1 * v1);
    mx = fmaxf(mx, l);
  }
  float denom = 0.f, ss0 = 0.f, ss1 = 0.f, sg0 = 0.f, sg1 = 0.f;
  for (int i = start; i <= end; ++i) {
    float x0 = xh[(size_t)i * DDIM + lane];
    float x1 = hi ? xh[(size_t)i * DDIM + 64 + lane] : 0.f;
    float l = wave_sum64(x0 * v0 + x1 * v1);   // identical on all lanes
    float p = expf(l - mx);
    denom += p;                                 // identical on all lanes
    float g0 = sigm(t2[(size_t)i * DDIM + lane] + t30);
    float g1 = hi ? sigm(t2[(size_t)i * DDIM + 64 + lane] + t31) : 0.f;
    float alpha = wave_sum64(q0 * g0 + q1 * g1) + qb;
    ss0 += p * x0; ss1 += p * x1;
    sg0 += alpha * x0; sg1 += alpha * x1;
  }
  float inv = 1.f / denom;
  float* Sc = Scat + (size_t)sid * 300;
  Sc[lane] = ss0 * inv;       if (hi) Sc[64 + lane] = ss1 * inv;
  Sc[100 + lane] = sg0;       if (hi) Sc[164 + lane] = sg1;
  Sc[200 + lane] = v0;        if (hi) Sc[264 + lane] = v1;
}

// ---------------------------------------------------------------- fp32 GEMM  C = A @ B^T
template <int KTOT, int MODE>
__global__ __launch_bounds__(256, 2) void gemm_abt(
    const float* __restrict__ A, const float* __restrict__ Bm,
    const float* __restrict__ bias, float* __restrict__ C,
    float* __restrict__ C2, int M, int Nout) {
  __shared__ float4 As4[25 * 128];  // 51.2 KB
  __shared__ float4 Bs4[25 * 64];   // 25.6 KB
  const int m0 = blockIdx.y * 128;
  const int n0 = blockIdx.x * 64;
  const int t = threadIdx.x;
  const int tx = t & 15;
  const int ty = t >> 4;
  float acc[8][4] = {};

  for (int kt = 0; kt < KTOT; kt += BK) {
    for (int idx = t; idx < 128 * 25; idx += 256) {
      int r = idx / 25, k4 = idx - r * 25;
      int ar = m0 + r; if (ar >= M) ar = M - 1;
      float4 v = *(const float4*)(A + (size_t)ar * KTOT + kt + 4 * k4);
      As4[k4 * 128 + (r ^ (k4 & 7))] = v;
    }
    for (int idx = t; idx < 64 * 25; idx += 256) {
      int r = idx / 25, k4 = idx - r * 25;
      int br = n0 + r;
      float4 v = make_float4(0.f, 0.f, 0.f, 0.f);
      if (br < Nout) v = *(const float4*)(Bm + (size_t)br * KTOT + kt + 4 * k4);
      Bs4[k4 * 64 + (r ^ (k4 & 7))] = v;
    }
    __syncthreads();
#pragma unroll 5
    for (int k4 = 0; k4 < 25; ++k4) {
      const int s = k4 & 7;
      float4 av[8], bv[4];
#pragma unroll
      for (int i = 0; i < 8; ++i) av[i] = As4[k4 * 128 + ((ty + 16 * i) ^ s)];
#pragma unroll
      for (int j = 0; j < 4; ++j) bv[j] = Bs4[k4 * 64 + ((tx + 16 * j) ^ s)];
#pragma unroll
      for (int i = 0; i < 8; ++i) {
#pragma unroll
        for (int j = 0; j < 4; ++j) {
          acc[i][j] = fmaf(av[i].x, bv[j].x, acc[i][j]);
          acc[i][j] = fmaf(av[i].y, bv[j].y, acc[i][j]);
          acc[i][j] = fmaf(av[i].z, bv[j].z, acc[i][j]);
          acc[i][j] = fmaf(av[i].w, bv[j].w, acc[i][j]);
        }
      }
    }
    __syncthreads();
  }

#pragma unroll
  for (int i = 0; i < 8; ++i) {
    int row = m0 + ty + 16 * i;
    if (row >= M) continue;
#pragma unroll
    for (int j = 0; j < 4; ++j) {
      int col = n0 + tx + 16 * j;
      if (col >= Nout) continue;
      float v = acc[i][j];
      if (MODE >= 1) v += bias[col];
      if (MODE == 2) {
        if (col < 200) {
          float* p = C + (size_t)row * 300 + col;
          *p = *p + v;
        } else {
          C2[(size_t)row * DDIM + (col - 200)] = v;
        }
      } else {
        C[(size_t)row * Nout + col] = v;
      }
    }
  }
}

// ---------------------------------------------------------------- bf16 split pack
// src [R,100] fp32 -> hi/lo packed fragments [RT][4 kt][64 lane][8 bf16]
// lane l of tile rt: row = rt*16 + (l&15), k = kt*32 + (l>>4)*8 + j (0 past 100)
__global__ void k_pack(const float* __restrict__ src, short8* __restrict__ hi,
                       short8* __restrict__ lo, int R, int RT) {
  int gid = blockIdx.x * 256 + threadIdx.x;
  if (gid >= RT * 4 * 64) return;
  int lane = gid & 63;
  int kt = (gid >> 6) & 3;
  int rt = gid >> 8;
  int r = rt * 16 + (lane & 15);
  if (r >= R) r = R - 1;
  int kb = kt * 32 + (lane >> 4) * 8;
  short8 h, l;
#pragma unroll
  for (int j = 0; j < 8; ++j) {
    int k = kb + j;
    float v = (k < DDIM) ? src[(size_t)r * DDIM + k] : 0.f;
    unsigned u = __float_as_uint(v);
    unsigned hb = (u + 0x7fffu + ((u >> 16) & 1u)) & 0xffff0000u;  // RNE bf16 (as fp32 bits)
    float res = v - __uint_as_float(hb);
    unsigned u2 = __float_as_uint(res);
    unsigned lb = (u2 + 0x7fffu + ((u2 >> 16) & 1u)) >> 16;
    h[j] = (short)(hb >> 16);
    l[j] = (short)lb;
  }
  hi[gid] = h;
  lo[gid] = l;
}

// ---------------------------------------------------------------- big MFMA GEMM
// out[M, NCOLS] = S @ emb^T via packed bf16 hi/lo fragments, split-precision
// (hi*hi + hi*lo + lo*hi). Block = 4 waves; wave owns 2 m-tiles; loop n-tiles.
__global__ __launch_bounds__(256) void k_bigmm(
    const short8* __restrict__ Ahi, const short8* __restrict__ Alo,
    const short8* __restrict__ Bhi, const short8* __restrict__ Blo,
    float* __restrict__ out, int NT, int NTCHUNK, int NCOLS) {
  const int lane = threadIdx.x & 63;
  const int wave = threadIdx.x >> 6;
  const int mt0 = blockIdx.y * 8 + wave * 2;

  short8 ah[2][4], al[2][4];
#pragma unroll
  for (int mi = 0; mi < 2; ++mi)
#pragma unroll
    for (int kt = 0; kt < 4; ++kt) {
      size_t off = ((size_t)(mt0 + mi) * 4 + kt) * 64 + lane;
      ah[mi][kt] = Ahi[off];
      al[mi][kt] = Alo[off];
    }

  const int nt0 = blockIdx.x * NTCHUNK;
  const int nt1 = min(NT, nt0 + NTCHUNK);
  const int r0 = (lane >> 4) * 4;
  const int c0 = lane & 15;

  for (int nt = nt0; nt < nt1; ++nt) {
    short8 bh[4], bl[4];
#pragma unroll
    for (int kt = 0; kt < 4; ++kt) {
      size_t off = ((size_t)nt * 4 + kt) * 64 + lane;
      bh[kt] = Bhi[off];
      bl[kt] = Blo[off];
    }
    f32x4 acc0 = {0.f, 0.f, 0.f, 0.f};
    f32x4 acc1 = {0.f, 0.f, 0.f, 0.f};
#pragma unroll
    for (int kt = 0; kt < 4; ++kt) {
      acc0 = __builtin_amdgcn_mfma_f32_16x16x32_bf16(ah[0][kt], bh[kt], acc0, 0, 0, 0);
      acc1 = __builtin_amdgcn_mfma_f32_16x16x32_bf16(ah[1][kt], bh[kt], acc1, 0, 0, 0);
      acc0 = __builtin_amdgcn_mfma_f32_16x16x32_bf16(ah[0][kt], bl[kt], acc0, 0, 0, 0);
      acc1 = __builtin_amdgcn_mfma_f32_16x16x32_bf16(ah[1][kt], bl[kt], acc1, 0, 0, 0);
      acc0 = __builtin_amdgcn_mfma_f32_16x16x32_bf16(al[0][kt], bh[kt], acc0, 0, 0, 0);
      acc1 = __builtin_amdgcn_mfma_f32_16x16x32_bf16(al[1][kt], bh[kt], acc1, 0, 0, 0);
    }
    int col = nt * 16 + c0;
    if (col < NCOLS) {
#pragma unroll
      for (int r = 0; r < 4; ++r) {
        __builtin_nontemporal_store(acc0[r], out + (size_t)(mt0 * 16 + r0 + r) * NCOLS + col);
        __builtin_nontemporal_store(acc1[r], out + (size_t)((mt0 + 1) * 16 + r0 + r) * NCOLS + col);
      }
    }
  }
}

// ---------------------------------------------------------------- launcher

extern "C" void kernel_launch(void* const* d_in, const int* in_sizes, int n_in,
                              void* d_out, int out_size, void* d_ws, size_t ws_size,
                              hipStream_t stream) {
  const int*   x      = (const int*)d_in[0];
  const int*   ei     = (const int*)d_in[1];
  const int*   batch  = (const int*)d_in[2];
  const float* emb    = (const float*)d_in[4];
  const float* conv_w = (const float*)d_in[5];
  const float* w_ih   = (const float*)d_in[6];
  const float* w_hh   = (const float*)d_in[7];
  const float* b_ih   = (const float*)d_in[8];
  const float* b_hh   = (const float*)d_in[9];
  const float* q_w    = (const float*)d_in[10];
  const float* q_b    = (const float*)d_in[11];
  const float* w2     = (const float*)d_in[12];
  const float* b2     = (const float*)d_in[13];
  const float* w3     = (const float*)d_in[14];
  const float* b3     = (const float*)d_in[15];
  const float* w4     = (const float*)d_in[16];
  const float* b4     = (const float*)d_in[17];

  const int N = in_sizes[0];            // 49152
  const int E = in_sizes[1] / 2;        // 98304
  const int NNODE = in_sizes[4] / DDIM; // 50000
  const int B = out_size / NNODE;       // 4096

  size_t ND = (size_t)N * DDIM;
  float* ws    = (float*)d_ws;
  float* h0    = ws;                 // [N,100]
  float* m_    = ws + ND;            // [N,100]  -> reused as xh
  float* agg   = ws + 2 * ND;        // [N,100]  -> reused as t2
  float* gi    = ws + 3 * ND;        // [N,300]
  float* hn    = ws + 6 * ND;        // [N,100]
  float* aux   = ws + 7 * ND;
  float* cwT   = aux;                          // [100,100]
  float* vn    = cwT + DDIM * DDIM;            // [B,100]
  float* t3v   = vn + (size_t)B * DDIM;        // [B,100]
  float* Scat  = t3v + (size_t)B * DDIM;       // [B,300]
  float* Sm    = Scat + 3 * (size_t)B * DDIM;  // [B,100]
  int*   lastI = (int*)(Sm + (size_t)B * DDIM);// [B]
  float* xh = m_;
  float* t2 = agg;

  const int MT = (B + 15) / 16;          // 256 m-tiles
  const int NT = (NNODE + 15) / 16;      // 3125 n-tiles
  short8* Ahi = (short8*)(lastI + B);
  short8* Alo = Ahi + (size_t)MT * 4 * 64;
  short8* Bhi = Alo + (size_t)MT * 4 * 64;
  short8* Blo = Bhi + (size_t)NT * 4 * 64;

  dim3 blk(256);
  int gy = (N + 127) / 128;   // 384
  int gyB = (B + 127) / 128;  // 32

  // pack emb early (independent of everything else)
  k_pack<<<(NT * 4 * 64 + 255) / 256, blk, 0, stream>>>(emb, Bhi, Blo, NNODE, NT);

  k_transpose<<<(DDIM * DDIM + 255) / 256, blk, 0, stream>>>(conv_w, cwT, DDIM);
  k_gather4<<<(N * 25 + 255) / 256, blk, 0, stream>>>(x, emb, (float4*)h0, (float4*)agg, N);
  gemm_abt<100, 0><<<dim3(2, gy), blk, 0, stream>>>(h0, cwT, nullptr, m_, nullptr, N, DDIM);
  k_scatter<<<(E * 25 + 255) / 256, blk, 0, stream>>>(ei, m_, agg, E);
  gemm_abt<100, 1><<<dim3(5, gy), blk, 0, stream>>>(agg, w_ih, b_ih, gi, nullptr, N, 300);
  gemm_abt<100, 2><<<dim3(5, gy), blk, 0, stream>>>(h0, w_hh, b_hh, gi, hn, N, 300);
  k_gru<<<(N * DDIM + 255) / 256, blk, 0, stream>>>(gi, hn, h0, xh, N);
  k_last<<<(N + 255) / 256, blk, 0, stream>>>(batch, lastI, N);
  k_vn<<<(B * 25 + 255) / 256, blk, 0, stream>>>(xh, lastI, (float4*)vn, B);
  gemm_abt<100, 1><<<dim3(2, gy), blk, 0, stream>>>(xh, w2, b2, t2, nullptr, N, DDIM);
  gemm_abt<100, 1><<<dim3(2, gyB), blk, 0, stream>>>(vn, w3, b3, t3v, nullptr, B, DDIM);
  k_session<<<(B + 3) / 4, blk, 0, stream>>>(xh, t2, vn, t3v, q_w, q_b, lastI, Scat, B);
  gemm_abt<300, 1><<<dim3(2, gyB), blk, 0, stream>>>(Scat, w4, b4, Sm, nullptr, B, DDIM);

  // pack S, then big MFMA GEMM: y = S @ emb^T
  k_pack<<<(MT * 4 * 64 + 255) / 256, blk, 0, stream>>>(Sm, Ahi, Alo, B, MT);
  const int NCHUNKS = 64;
  const int NTCHUNK = (NT + NCHUNKS - 1) / NCHUNKS;  // 49
  k_bigmm<<<dim3(NCHUNKS, (B + 127) / 128), blk, 0, stream>>>(
      Ahi, Alo, Bhi, Blo, (float*)d_out, NT, NTCHUNK, NNODE);
}

// Round 4
// 639.594 us; speedup vs baseline: 2.1040x; 1.2498x over previous
//
#include <hip/hip_runtime.h>
#include <math.h>

#define DDIM 100   // embed dim
#define BK   100   // K-chunk staged in LDS for fp32 GEMM (KTOT is 100 or 300)

using short8 = __attribute__((ext_vector_type(8))) short;
using f32x4  = __attribute__((ext_vector_type(4))) float;

// ---------------------------------------------------------------- utilities

__device__ __forceinline__ float wave_sum64(float v) {
#pragma unroll
  for (int o = 32; o > 0; o >>= 1) v += __shfl_xor(v, o, 64);
  return v;
}

__device__ __forceinline__ float sigm(float x) { return 1.f / (1.f + expf(-x)); }

__device__ __forceinline__ f32x4 mfma16(short8 a, short8 b, f32x4 c) {
  return __builtin_amdgcn_mfma_f32_16x16x32_bf16(a, b, c, 0, 0, 0);
}

// RNE bf16 split: v ~= hi + lo, |err| ~ 2^-18 |v|
__device__ __forceinline__ void bf16split(float v, short& h, short& l) {
  unsigned u = __float_as_uint(v);
  unsigned hb = (u + 0x7fffu + ((u >> 16) & 1u)) & 0xffff0000u;
  float res = v - __uint_as_float(hb);
  unsigned u2 = __float_as_uint(res);
  h = (short)(hb >> 16);
  l = (short)((u2 + 0x7fffu + ((u2 >> 16) & 1u)) >> 16);
}

// ---------------------------------------------------------------- elementwise

// h0 = emb[x-1], aggH = 0
__global__ void k_gather4(const int* __restrict__ x, const float* __restrict__ emb,
                          float4* __restrict__ h0, float4* __restrict__ aggH, int n) {
  int i = blockIdx.x * 256 + threadIdx.x;
  if (i < n * 25) {
    int node = i / 25, c = i - node * 25;
    h0[i] = *(const float4*)(emb + (size_t)(x[node] - 1) * DDIM + 4 * c);
    aggH[i] = make_float4(0.f, 0.f, 0.f, 0.f);
  }
}

// aggH[dst] += h0[src]
__global__ void k_scatter(const int* __restrict__ ei, const float* __restrict__ src_rows,
                          float* __restrict__ aggH, int E) {
  int i = blockIdx.x * 256 + threadIdx.x;
  if (i < E * 25) {
    int e = i / 25, c = i - e * 25;
    int s = ei[e], d = ei[E + e];
    float4 v = *(const float4*)(src_rows + (size_t)s * DDIM + 4 * c);
    float* ap = aggH + (size_t)d * DDIM + 4 * c;
    atomicAdd(ap + 0, v.x); atomicAdd(ap + 1, v.y);
    atomicAdd(ap + 2, v.z); atomicAdd(ap + 3, v.w);
  }
}

__global__ void k_last(const int* __restrict__ batch, int* __restrict__ last_idx, int n) {
  int i = blockIdx.x * 256 + threadIdx.x;
  if (i < n) {
    if (i == n - 1 || batch[i + 1] != batch[i]) last_idx[batch[i]] = i;
  }
}

__global__ void k_vn(const float* __restrict__ xh, const int* __restrict__ last_idx,
                     float4* __restrict__ vn, int b) {
  int i = blockIdx.x * 256 + threadIdx.x;
  if (i < b * 25) {
    int s = i / 25, c = i - s * 25;
    vn[i] = *(const float4*)(xh + (size_t)last_idx[s] * DDIM + 4 * c);
  }
}

// one wave per session: softmax pooling (S_s), gated pooling (S_g), v_n
__global__ __launch_bounds__(256) void k_session(
    const float* __restrict__ xh, const float* __restrict__ t2,
    const float* __restrict__ vn, const float* __restrict__ t3v,
    const float* __restrict__ q_w, const float* __restrict__ q_b,
    const int* __restrict__ last_idx, float* __restrict__ Scat, int B) {
  int sid = blockIdx.x * 4 + (threadIdx.x >> 6);
  if (sid >= B) return;
  int lane = threadIdx.x & 63;
  bool hi = lane < (DDIM - 64);  // 36
  int start = (sid == 0) ? 0 : last_idx[sid - 1] + 1;
  int end = last_idx[sid];

  float v0 = vn[(size_t)sid * DDIM + lane];
  float v1 = hi ? vn[(size_t)sid * DDIM + 64 + lane] : 0.f;
  float t30 = t3v[(size_t)sid * DDIM + lane];
  float t31 = hi ? t3v[(size_t)sid * DDIM + 64 + lane] : 0.f;
  float q0 = q_w[lane];
  float q1 = hi ? q_w[64 + lane] : 0.f;
  float qb = q_b[0];

  float mx = -INFINITY;
  for (int i = start; i <= end; ++i) {
    float x0 = xh[(size_t)i * DDIM + lane];
    float x1 = hi ? xh[(size_t)i * DDIM + 64 + lane] : 0.f;
    float l = wave_sum64(x0 * v0 + x1 * v1);
    mx = fmaxf(mx, l);
  }
  float denom = 0.f, ss0 = 0.f, ss1 = 0.f, sg0 = 0.f, sg1 = 0.f;
  for (int i = start; i <= end; ++i) {
    float x0 = xh[(size_t)i * DDIM + lane];
    float x1 = hi ? xh[(size_t)i * DDIM + 64 + lane] : 0.f;
    float l = wave_sum64(x0 * v0 + x1 * v1);
    float p = expf(l - mx);
    denom += p;
    float g0 = sigm(t2[(size_t)i * DDIM + lane] + t30);
    float g1 = hi ? sigm(t2[(size_t)i * DDIM + 64 + lane] + t31) : 0.f;
    float alpha = wave_sum64(q0 * g0 + q1 * g1) + qb;
    ss0 += p * x0; ss1 += p * x1;
    sg0 += alpha * x0; sg1 += alpha * x1;
  }
  float inv = 1.f / denom;
  float* Sc = Scat + (size_t)sid * 300;
  Sc[lane] = ss0 * inv;       if (hi) Sc[64 + lane] = ss1 * inv;
  Sc[100 + lane] = sg0;       if (hi) Sc[164 + lane] = sg1;
  Sc[200 + lane] = v0;        if (hi) Sc[264 + lane] = v1;
}

// ---------------------------------------------------------------- fp32 GEMM  C = A @ B^T
// K-chunked LDS staging (BK=100 -> 76.8 KB LDS). Used for t3v and Sm only.
template <int KTOT, int MODE>
__global__ __launch_bounds__(256, 2) void gemm_abt(
    const float* __restrict__ A, const float* __restrict__ Bm,
    const float* __restrict__ bias, float* __restrict__ C,
    float* __restrict__ C2, int M, int Nout) {
  __shared__ float4 As4[25 * 128];  // 51.2 KB
  __shared__ float4 Bs4[25 * 64];   // 25.6 KB
  const int m0 = blockIdx.y * 128;
  const int n0 = blockIdx.x * 64;
  const int t = threadIdx.x;
  const int tx = t & 15;
  const int ty = t >> 4;
  float acc[8][4] = {};

  for (int kt = 0; kt < KTOT; kt += BK) {
    for (int idx = t; idx < 128 * 25; idx += 256) {
      int r = idx / 25, k4 = idx - r * 25;
      int ar = m0 + r; if (ar >= M) ar = M - 1;
      float4 v = *(const float4*)(A + (size_t)ar * KTOT + kt + 4 * k4);
      As4[k4 * 128 + (r ^ (k4 & 7))] = v;
    }
    for (int idx = t; idx < 64 * 25; idx += 256) {
      int r = idx / 25, k4 = idx - r * 25;
      int br = n0 + r;
      float4 v = make_float4(0.f, 0.f, 0.f, 0.f);
      if (br < Nout) v = *(const float4*)(Bm + (size_t)br * KTOT + kt + 4 * k4);
      Bs4[k4 * 64 + (r ^ (k4 & 7))] = v;
    }
    __syncthreads();
#pragma unroll 5
    for (int k4 = 0; k4 < 25; ++k4) {
      const int s = k4 & 7;
      float4 av[8], bv[4];
#pragma unroll
      for (int i = 0; i < 8; ++i) av[i] = As4[k4 * 128 + ((ty + 16 * i) ^ s)];
#pragma unroll
      for (int j = 0; j < 4; ++j) bv[j] = Bs4[k4 * 64 + ((tx + 16 * j) ^ s)];
#pragma unroll
      for (int i = 0; i < 8; ++i) {
#pragma unroll
        for (int j = 0; j < 4; ++j) {
          acc[i][j] = fmaf(av[i].x, bv[j].x, acc[i][j]);
          acc[i][j] = fmaf(av[i].y, bv[j].y, acc[i][j]);
          acc[i][j] = fmaf(av[i].z, bv[j].z, acc[i][j]);
          acc[i][j] = fmaf(av[i].w, bv[j].w, acc[i][j]);
        }
      }
    }
    __syncthreads();
  }

#pragma unroll
  for (int i = 0; i < 8; ++i) {
    int row = m0 + ty + 16 * i;
    if (row >= M) continue;
#pragma unroll
    for (int j = 0; j < 4; ++j) {
      int col = n0 + tx + 16 * j;
      if (col >= Nout) continue;
      float v = acc[i][j];
      if (MODE >= 1) v += bias[col];
      C[(size_t)row * Nout + col] = v;
    }
  }
}

// ---------------------------------------------------------------- bf16 split pack (stride-100 rows)
// src [R,100] fp32 -> hi/lo fragments [RT][4 kt][64 lane][8]
// lane l of tile rt: row = rt*16 + (l&15), k = kt*32 + (l>>4)*8 + j (0 past 100)
__global__ void k_pack(const float* __restrict__ src, short8* __restrict__ hi,
                       short8* __restrict__ lo, int R, int RT) {
  int gid = blockIdx.x * 256 + threadIdx.x;
  if (gid >= RT * 4 * 64) return;
  int lane = gid & 63;
  int kt = (gid >> 6) & 3;
  int rt = gid >> 8;
  int r = rt * 16 + (lane & 15);
  if (r >= R) r = R - 1;
  int kb = kt * 32 + (lane >> 4) * 8;
  short8 h, l;
#pragma unroll
  for (int j = 0; j < 8; ++j) {
    int k = kb + j;
    float v = (k < DDIM) ? src[(size_t)r * DDIM + k] : 0.f;
    short hh, ll;
    bf16split(v, hh, ll);
    h[j] = hh; l[j] = ll;
  }
  hi[gid] = h;
  lo[gid] = l;
}

// ---------------------------------------------------------------- weight pack
// 7 fragment sets, each [7 nt][4 kt][64 lane] short8 (output-col d = nt*16+(lane&15),
// k = kt*32+(lane>>4)*8+j, zero past 100):
// s=0..2: Wc thirds, Wc[c,k] = dot(w_ih[c,:], conv_w[k,:])  (c = s*100+d)
// s=3..5: w_hh thirds ; s=6: w2
__global__ void k_packW(const float* __restrict__ w_ih, const float* __restrict__ conv_w,
                        const float* __restrict__ w_hh, const float* __restrict__ w2,
                        short8* __restrict__ Whi, short8* __restrict__ Wlo) {
  int gid = blockIdx.x * 256 + threadIdx.x;
  if (gid >= 7 * 7 * 4 * 64) return;
  int lane = gid & 63;
  int kt = (gid >> 6) & 3;
  int snt = gid >> 8;
  int nt = snt % 7;
  int s = snt / 7;
  int d = nt * 16 + (lane & 15);
  int k0 = kt * 32 + (lane >> 4) * 8;
  short8 h, l;
#pragma unroll
  for (int j = 0; j < 8; ++j) {
    int k = k0 + j;
    float v = 0.f;
    if (d < 100 && k < 100) {
      if (s < 3) {
        const float* wr = w_ih + (size_t)(s * 100 + d) * 100;
        const float* cr = conv_w + (size_t)k * 100;
        float acc = 0.f;
        for (int t = 0; t < 100; ++t) acc = fmaf(wr[t], cr[t], acc);
        v = acc;
      } else if (s < 6) {
        v = w_hh[(size_t)((s - 3) * 100 + d) * 100 + k];
      } else {
        v = w2[(size_t)d * 100 + k];
      }
    }
    short hh, ll;
    bf16split(v, hh, ll);
    h[j] = hh; l[j] = ll;
  }
  Whi[gid] = h;
  Wlo[gid] = l;
}

// load + convert A fragments for one 16-row m-tile (K=100, padded to 128)
__device__ __forceinline__ void load_afrags(const float* __restrict__ A, int rowBase,
                                            int lane, short8 ah[4], short8 al[4]) {
  int r = rowBase + (lane & 15);
  int g = lane >> 4;
#pragma unroll
  for (int kt = 0; kt < 4; ++kt) {
    int k0 = kt * 32 + g * 8;
    float4 f0 = make_float4(0.f, 0.f, 0.f, 0.f);
    float4 f1 = make_float4(0.f, 0.f, 0.f, 0.f);
    if (k0 < 100)     f0 = *(const float4*)(A + (size_t)r * DDIM + k0);
    if (k0 + 4 < 100) f1 = *(const float4*)(A + (size_t)r * DDIM + k0 + 4);
    float v[8] = {f0.x, f0.y, f0.z, f0.w, f1.x, f1.y, f1.z, f1.w};
    short8 h, l;
#pragma unroll
    for (int j = 0; j < 8; ++j) {
      short hh, ll;
      bf16split(v[j], hh, ll);
      h[j] = hh; l[j] = ll;
    }
    ah[kt] = h; al[kt] = l;
  }
}

// ---------------------------------------------------------------- fused GGC+GRU
// xh = relu(GRU(gi, gh, h0)) where gi = aggH@Wc^T + b_ih, gh = h0@w_hh^T + b_hh,
// all 6 Nout=100 dot-sets via MFMA (split bf16), nothing intermediate to HBM.
__global__ __launch_bounds__(256) void k_grufused(
    const float* __restrict__ aggH, const float* __restrict__ h0,
    const short8* __restrict__ Whi, const short8* __restrict__ Wlo,
    const float* __restrict__ b_ih, const float* __restrict__ b_hh,
    float* __restrict__ xh) {
  const int lane = threadIdx.x & 63;
  const int wave = threadIdx.x >> 6;
  const int rowBase = blockIdx.x * 64 + wave * 16;
  short8 aIh[4], aIl[4], aHh[4], aHl[4];
  load_afrags(aggH, rowBase, lane, aIh, aIl);
  load_afrags(h0, rowBase, lane, aHh, aHl);
  const int c0 = lane & 15;
  const int r0 = (lane >> 4) * 4;

  for (int nt = 0; nt < 7; ++nt) {
    int d = nt * 16 + c0;
    f32x4 acc[6];
#pragma unroll
    for (int s = 0; s < 6; ++s) {
      f32x4 a = {0.f, 0.f, 0.f, 0.f};
#pragma unroll
      for (int kt = 0; kt < 4; ++kt) {
        size_t off = (((size_t)s * 7 + nt) * 4 + kt) * 64 + lane;
        short8 bh = Whi[off];
        short8 bl = Wlo[off];
        if (s < 3) {
          a = mfma16(aIh[kt], bh, a);
          a = mfma16(aIh[kt], bl, a);
          a = mfma16(aIl[kt], bh, a);
        } else {
          a = mfma16(aHh[kt], bh, a);
          a = mfma16(aHh[kt], bl, a);
          a = mfma16(aHl[kt], bh, a);
        }
      }
      acc[s] = a;
    }
    if (d < 100) {
      float bir = b_ih[d], biz = b_ih[100 + d], bin_ = b_ih[200 + d];
      float bhr = b_hh[d], bhz = b_hh[100 + d], bhn = b_hh[200 + d];
#pragma unroll
      for (int ri = 0; ri < 4; ++ri) {
        int row = rowBase + r0 + ri;
        float r = sigm(acc[0][ri] + bir + acc[3][ri] + bhr);
        float z = sigm(acc[1][ri] + biz + acc[4][ri] + bhz);
        float n = tanhf(acc[2][ri] + bin_ + r * (acc[5][ri] + bhn));
        float h0v = h0[(size_t)row * DDIM + d];
        float v = (1.f - z) * n + z * h0v;
        xh[(size_t)row * DDIM + d] = v > 0.f ? v : 0.f;
      }
    }
  }
}

// t2 = A @ w2^T + b2  (Nout=100) via MFMA, W frags = set 6 of the pack
__global__ __launch_bounds__(256) void k_mm100(
    const float* __restrict__ A, const short8* __restrict__ Whi,
    const short8* __restrict__ Wlo, const float* __restrict__ bias,
    float* __restrict__ out) {
  const int lane = threadIdx.x & 63;
  const int wave = threadIdx.x >> 6;
  const int rowBase = blockIdx.x * 64 + wave * 16;
  short8 ah[4], al[4];
  load_afrags(A, rowBase, lane, ah, al);
  const int c0 = lane & 15;
  const int r0 = (lane >> 4) * 4;

  for (int nt = 0; nt < 7; ++nt) {
    int d = nt * 16 + c0;
    f32x4 a = {0.f, 0.f, 0.f, 0.f};
#pragma unroll
    for (int kt = 0; kt < 4; ++kt) {
      size_t off = (((size_t)6 * 7 + nt) * 4 + kt) * 64 + lane;
      short8 bh = Whi[off];
      short8 bl = Wlo[off];
      a = mfma16(ah[kt], bh, a);
      a = mfma16(ah[kt], bl, a);
      a = mfma16(al[kt], bh, a);
    }
    if (d < 100) {
      float b = bias[d];
#pragma unroll
      for (int ri = 0; ri < 4; ++ri) {
        int row = rowBase + r0 + ri;
        out[(size_t)row * DDIM + d] = a[ri] + b;
      }
    }
  }
}

// ---------------------------------------------------------------- big MFMA GEMM
// out[M, NCOLS] = S @ emb^T via packed bf16 hi/lo fragments, split-precision.
// Register double-buffered prefetch of B fragments.
__global__ __launch_bounds__(256) void k_bigmm(
    const short8* __restrict__ Ahi, const short8* __restrict__ Alo,
    const short8* __restrict__ Bhi, const short8* __restrict__ Blo,
    float* __restrict__ out, int NT, int NTCHUNK, int NCOLS) {
  const int lane = threadIdx.x & 63;
  const int wave = threadIdx.x >> 6;
  const int mt0 = blockIdx.y * 8 + wave * 2;

  short8 ah[2][4], al[2][4];
#pragma unroll
  for (int mi = 0; mi < 2; ++mi)
#pragma unroll
    for (int kt = 0; kt < 4; ++kt) {
      size_t off = ((size_t)(mt0 + mi) * 4 + kt) * 64 + lane;
      ah[mi][kt] = Ahi[off];
      al[mi][kt] = Alo[off];
    }

  const int nt0 = blockIdx.x * NTCHUNK;
  const int nt1 = min(NT, nt0 + NTCHUNK);
  const int r0 = (lane >> 4) * 4;
  const int c0 = lane & 15;

  auto loadB = [&](short8 (&bh)[4], short8 (&bl)[4], int nt) {
#pragma unroll
    for (int kt = 0; kt < 4; ++kt) {
      size_t off = ((size_t)nt * 4 + kt) * 64 + lane;
      bh[kt] = Bhi[off];
      bl[kt] = Blo[off];
    }
  };
  auto compute = [&](short8 (&bh)[4], short8 (&bl)[4], int nt) {
    f32x4 acc0 = {0.f, 0.f, 0.f, 0.f};
    f32x4 acc1 = {0.f, 0.f, 0.f, 0.f};
#pragma unroll
    for (int kt = 0; kt < 4; ++kt) {
      acc0 = mfma16(ah[0][kt], bh[kt], acc0);
      acc1 = mfma16(ah[1][kt], bh[kt], acc1);
      acc0 = mfma16(ah[0][kt], bl[kt], acc0);
      acc1 = mfma16(ah[1][kt], bl[kt], acc1);
      acc0 = mfma16(al[0][kt], bh[kt], acc0);
      acc1 = mfma16(al[1][kt], bh[kt], acc1);
    }
    int col = nt * 16 + c0;
#pragma unroll
    for (int r = 0; r < 4; ++r) {
      __builtin_nontemporal_store(acc0[r], out + (size_t)(mt0 * 16 + r0 + r) * NCOLS + col);
      __builtin_nontemporal_store(acc1[r], out + (size_t)((mt0 + 1) * 16 + r0 + r) * NCOLS + col);
    }
  };

  short8 bhA[4], blA[4], bhB[4], blB[4];
  if (nt0 < nt1) loadB(bhA, blA, nt0);
  for (int nt = nt0; nt < nt1;) {
    if (nt + 1 < nt1) loadB(bhB, blB, nt + 1);
    compute(bhA, blA, nt);
    ++nt;
    if (nt >= nt1) break;
    if (nt + 1 < nt1) loadB(bhA, blA, nt + 1);
    compute(bhB, blB, nt);
    ++nt;
  }
}

// ---------------------------------------------------------------- launcher

extern "C" void kernel_launch(void* const* d_in, const int* in_sizes, int n_in,
                              void* d_out, int out_size, void* d_ws, size_t ws_size,
                              hipStream_t stream) {
  const int*   x      = (const int*)d_in[0];
  const int*   ei     = (const int*)d_in[1];
  const int*   batch  = (const int*)d_in[2];
  const float* emb    = (const float*)d_in[4];
  const float* conv_w = (const float*)d_in[5];
  const float* w_ih   = (const float*)d_in[6];
  const float* w_hh   = (const float*)d_in[7];
  const float* b_ih   = (const float*)d_in[8];
  const float* b_hh   = (const float*)d_in[9];
  const float* q_w    = (const float*)d_in[10];
  const float* q_b    = (const float*)d_in[11];
  const float* w2     = (const float*)d_in[12];
  const float* b2     = (const float*)d_in[13];
  const float* w3     = (const float*)d_in[14];
  const float* b3     = (const float*)d_in[15];
  const float* w4     = (const float*)d_in[16];
  const float* b4     = (const float*)d_in[17];

  const int N = in_sizes[0];            // 49152
  const int E = in_sizes[1] / 2;        // 98304
  const int NNODE = in_sizes[4] / DDIM; // 50000
  const int B = out_size / NNODE;       // 4096

  size_t ND = (size_t)N * DDIM;
  float* ws   = (float*)d_ws;
  float* h0   = ws;            // [N,100]
  float* aggH = ws + ND;       // [N,100]
  float* xh   = ws + 2 * ND;   // [N,100]
  float* t2   = ws + 3 * ND;   // [N,100]
  float* aux  = ws + 4 * ND;
  float* vn   = aux;                           // [B,100]
  float* t3v  = vn + (size_t)B * DDIM;         // [B,100]
  float* Scat = t3v + (size_t)B * DDIM;        // [B,300]
  float* Sm   = Scat + 3 * (size_t)B * DDIM;   // [B,100]
  int*   lastI = (int*)(Sm + (size_t)B * DDIM);// [B]

  const int MT = (B + 15) / 16;          // 256
  const int NT = (NNODE + 15) / 16;      // 3125
  short8* Whi = (short8*)(lastI + B);    // 7 sets x [7][4][64]
  short8* Wlo = Whi + 7 * 7 * 4 * 64;
  short8* Ahi = Wlo + 7 * 7 * 4 * 64;
  short8* Alo = Ahi + (size_t)MT * 4 * 64;
  short8* Bhi = Alo + (size_t)MT * 4 * 64;
  short8* Blo = Bhi + (size_t)NT * 4 * 64;

  dim3 blk(256);
  int gyB = (B + 127) / 128;  // 32

  // independent prep
  k_pack<<<(NT * 4 * 64 + 255) / 256, blk, 0, stream>>>(emb, Bhi, Blo, NNODE, NT);
  k_packW<<<(7 * 7 * 4 * 64 + 255) / 256, blk, 0, stream>>>(w_ih, conv_w, w_hh, w2, Whi, Wlo);
  k_last<<<(N + 255) / 256, blk, 0, stream>>>(batch, lastI, N);

  // node chain
  k_gather4<<<(N * 25 + 255) / 256, blk, 0, stream>>>(x, emb, (float4*)h0, (float4*)aggH, N);
  k_scatter<<<(E * 25 + 255) / 256, blk, 0, stream>>>(ei, h0, aggH, E);
  k_grufused<<<N / 64, blk, 0, stream>>>(aggH, h0, Whi, Wlo, b_ih, b_hh, xh);
  k_vn<<<(B * 25 + 255) / 256, blk, 0, stream>>>(xh, lastI, (float4*)vn, B);
  k_mm100<<<N / 64, blk, 0, stream>>>(xh, Whi, Wlo, b2, t2);
  gemm_abt<100, 1><<<dim3(2, gyB), blk, 0, stream>>>(vn, w3, b3, t3v, nullptr, B, DDIM);
  k_session<<<(B + 3) / 4, blk, 0, stream>>>(xh, t2, vn, t3v, q_w, q_b, lastI, Scat, B);
  gemm_abt<300, 1><<<dim3(2, gyB), blk, 0, stream>>>(Scat, w4, b4, Sm, nullptr, B, DDIM);

  // final big GEMM
  k_pack<<<(MT * 4 * 64 + 255) / 256, blk, 0, stream>>>(Sm, Ahi, Alo, B, MT);
  const int NCHUNKS = 64;
  const int NTCHUNK = (NT + NCHUNKS - 1) / NCHUNKS;  // 49
  k_bigmm<<<dim3(NCHUNKS, (B + 127) / 128), blk, 0, stream>>>(
      Ahi, Alo, Bhi, Blo, (float*)d_out, NT, NTCHUNK, NNODE);
}

// Round 5
// 604.013 us; speedup vs baseline: 2.2280x; 1.0589x over previous
//
#include <hip/hip_runtime.h>
#include <math.h>

#define DDIM 100   // embed dim
#define BK   100   // K-chunk staged in LDS for fp32 GEMM (KTOT is 100 or 300)
#define PFD  4     // k_bigmm LDS ring depth

using short8 = __attribute__((ext_vector_type(8))) short;
using f32x4  = __attribute__((ext_vector_type(4))) float;

// ---------------------------------------------------------------- utilities

__device__ __forceinline__ float wave_sum64(float v) {
#pragma unroll
  for (int o = 32; o > 0; o >>= 1) v += __shfl_xor(v, o, 64);
  return v;
}

__device__ __forceinline__ float sigm(float x) { return 1.f / (1.f + expf(-x)); }

__device__ __forceinline__ f32x4 mfma16(short8 a, short8 b, f32x4 c) {
  return __builtin_amdgcn_mfma_f32_16x16x32_bf16(a, b, c, 0, 0, 0);
}

// async global->LDS, 16B per lane: LDS dest = uniform base + lane*16,
// global src = per-lane pointer (m97/m104 semantics)
__device__ __forceinline__ void gld_lds16(const void* g, void* l) {
  __builtin_amdgcn_global_load_lds(
      (const __attribute__((address_space(1))) void*)g,
      (__attribute__((address_space(3))) void*)l, 16, 0, 0);
}

// RNE bf16 split: v ~= hi + lo, |err| ~ 2^-18 |v|
__device__ __forceinline__ void bf16split(float v, short& h, short& l) {
  unsigned u = __float_as_uint(v);
  unsigned hb = (u + 0x7fffu + ((u >> 16) & 1u)) & 0xffff0000u;
  float res = v - __uint_as_float(hb);
  unsigned u2 = __float_as_uint(res);
  h = (short)(hb >> 16);
  l = (short)((u2 + 0x7fffu + ((u2 >> 16) & 1u)) >> 16);
}

// ---------------------------------------------------------------- elementwise

// h0 = emb[x-1], aggH = 0, plus last-node-per-session detection
__global__ void k_gather4(const int* __restrict__ x, const float* __restrict__ emb,
                          float4* __restrict__ h0, float4* __restrict__ aggH,
                          const int* __restrict__ batch, int* __restrict__ last_idx,
                          int n) {
  int i = blockIdx.x * 256 + threadIdx.x;
  if (i < n * 25) {
    int node = i / 25, c = i - node * 25;
    h0[i] = *(const float4*)(emb + (size_t)(x[node] - 1) * DDIM + 4 * c);
    aggH[i] = make_float4(0.f, 0.f, 0.f, 0.f);
  }
  if (i < n) {
    if (i == n - 1 || batch[i + 1] != batch[i]) last_idx[batch[i]] = i;
  }
}

// aggH[dst] += h0[src]
__global__ void k_scatter(const int* __restrict__ ei, const float* __restrict__ src_rows,
                          float* __restrict__ aggH, int E) {
  int i = blockIdx.x * 256 + threadIdx.x;
  if (i < E * 25) {
    int e = i / 25, c = i - e * 25;
    int s = ei[e], d = ei[E + e];
    float4 v = *(const float4*)(src_rows + (size_t)s * DDIM + 4 * c);
    float* ap = aggH + (size_t)d * DDIM + 4 * c;
    atomicAdd(ap + 0, v.x); atomicAdd(ap + 1, v.y);
    atomicAdd(ap + 2, v.z); atomicAdd(ap + 3, v.w);
  }
}

// one wave per session: ONE-PASS online softmax pooling (S_s), gated pooling (S_g), v_n
__global__ __launch_bounds__(256) void k_session(
    const float* __restrict__ xh, const float* __restrict__ t2,
    const float* __restrict__ t3v,
    const float* __restrict__ q_w, const float* __restrict__ q_b,
    const int* __restrict__ last_idx, float* __restrict__ Scat, int B) {
  int sid = blockIdx.x * 4 + (threadIdx.x >> 6);
  if (sid >= B) return;
  int lane = threadIdx.x & 63;
  bool hi = lane < (DDIM - 64);  // 36
  int start = (sid == 0) ? 0 : last_idx[sid - 1] + 1;
  int end = last_idx[sid];

  float v0 = xh[(size_t)end * DDIM + lane];
  float v1 = hi ? xh[(size_t)end * DDIM + 64 + lane] : 0.f;
  float t30 = t3v[(size_t)sid * DDIM + lane];
  float t31 = hi ? t3v[(size_t)sid * DDIM + 64 + lane] : 0.f;
  float q0 = q_w[lane];
  float q1 = hi ? q_w[64 + lane] : 0.f;
  float qb = q_b[0];

  float m = -INFINITY, denom = 0.f;
  float ss0 = 0.f, ss1 = 0.f, sg0 = 0.f, sg1 = 0.f;
  for (int i = start; i <= end; ++i) {
    float x0 = xh[(size_t)i * DDIM + lane];
    float x1 = hi ? xh[(size_t)i * DDIM + 64 + lane] : 0.f;
    float l = wave_sum64(x0 * v0 + x1 * v1);   // uniform across lanes
    float mn = fmaxf(m, l);
    float cf = expf(m - mn);                   // 0 on first iter (m=-inf)
    float p = expf(l - mn);
    denom = denom * cf + p;
    ss0 = ss0 * cf + p * x0;
    ss1 = ss1 * cf + p * x1;
    m = mn;
    float g0 = sigm(t2[(size_t)i * DDIM + lane] + t30);
    float g1 = hi ? sigm(t2[(size_t)i * DDIM + 64 + lane] + t31) : 0.f;
    float alpha = wave_sum64(q0 * g0 + q1 * g1) + qb;
    sg0 += alpha * x0; sg1 += alpha * x1;
  }
  float inv = 1.f / denom;
  float* Sc = Scat + (size_t)sid * 300;
  Sc[lane] = ss0 * inv;       if (hi) Sc[64 + lane] = ss1 * inv;
  Sc[100 + lane] = sg0;       if (hi) Sc[164 + lane] = sg1;
  Sc[200 + lane] = v0;        if (hi) Sc[264 + lane] = v1;
}

// ---------------------------------------------------------------- fp32 GEMM  C = A @ B^T
// K-chunked LDS staging (BK=100 -> 76.8 KB). rowidx (optional) gathers A rows.
template <int KTOT, int MODE>
__global__ __launch_bounds__(256, 2) void gemm_abt(
    const float* __restrict__ A, const float* __restrict__ Bm,
    const float* __restrict__ bias, float* __restrict__ C,
    const int* __restrict__ rowidx, int M, int Nout) {
  __shared__ float4 As4[25 * 128];  // 51.2 KB
  __shared__ float4 Bs4[25 * 64];   // 25.6 KB
  const int m0 = blockIdx.y * 128;
  const int n0 = blockIdx.x * 64;
  const int t = threadIdx.x;
  const int tx = t & 15;
  const int ty = t >> 4;
  float acc[8][4] = {};

  for (int kt = 0; kt < KTOT; kt += BK) {
    for (int idx = t; idx < 128 * 25; idx += 256) {
      int r = idx / 25, k4 = idx - r * 25;
      int ar = m0 + r; if (ar >= M) ar = M - 1;
      if (rowidx) ar = rowidx[ar];
      float4 v = *(const float4*)(A + (size_t)ar * KTOT + kt + 4 * k4);
      As4[k4 * 128 + (r ^ (k4 & 7))] = v;
    }
    for (int idx = t; idx < 64 * 25; idx += 256) {
      int r = idx / 25, k4 = idx - r * 25;
      int br = n0 + r;
      float4 v = make_float4(0.f, 0.f, 0.f, 0.f);
      if (br < Nout) v = *(const float4*)(Bm + (size_t)br * KTOT + kt + 4 * k4);
      Bs4[k4 * 64 + (r ^ (k4 & 7))] = v;
    }
    __syncthreads();
#pragma unroll 5
    for (int k4 = 0; k4 < 25; ++k4) {
      const int s = k4 & 7;
      float4 av[8], bv[4];
#pragma unroll
      for (int i = 0; i < 8; ++i) av[i] = As4[k4 * 128 + ((ty + 16 * i) ^ s)];
#pragma unroll
      for (int j = 0; j < 4; ++j) bv[j] = Bs4[k4 * 64 + ((tx + 16 * j) ^ s)];
#pragma unroll
      for (int i = 0; i < 8; ++i) {
#pragma unroll
        for (int j = 0; j < 4; ++j) {
          acc[i][j] = fmaf(av[i].x, bv[j].x, acc[i][j]);
          acc[i][j] = fmaf(av[i].y, bv[j].y, acc[i][j]);
          acc[i][j] = fmaf(av[i].z, bv[j].z, acc[i][j]);
          acc[i][j] = fmaf(av[i].w, bv[j].w, acc[i][j]);
        }
      }
    }
    __syncthreads();
  }

#pragma unroll
  for (int i = 0; i < 8; ++i) {
    int row = m0 + ty + 16 * i;
    if (row >= M) continue;
#pragma unroll
    for (int j = 0; j < 4; ++j) {
      int col = n0 + tx + 16 * j;
      if (col >= Nout) continue;
      float v = acc[i][j];
      if (MODE >= 1) v += bias[col];
      C[(size_t)row * Nout + col] = v;
    }
  }
}

// ---------------------------------------------------------------- bf16 split pack
__global__ void k_pack(const float* __restrict__ src, short8* __restrict__ hi,
                       short8* __restrict__ lo, int R, int RT) {
  int gid = blockIdx.x * 256 + threadIdx.x;
  if (gid >= RT * 4 * 64) return;
  int lane = gid & 63;
  int kt = (gid >> 6) & 3;
  int rt = gid >> 8;
  int r = rt * 16 + (lane & 15);
  if (r >= R) r = R - 1;
  int kb = kt * 32 + (lane >> 4) * 8;
  short8 h, l;
#pragma unroll
  for (int j = 0; j < 8; ++j) {
    int k = kb + j;
    float v = (k < DDIM) ? src[(size_t)r * DDIM + k] : 0.f;
    short hh, ll;
    bf16split(v, hh, ll);
    h[j] = hh; l[j] = ll;
  }
  hi[gid] = h;
  lo[gid] = l;
}

// ---------------------------------------------------------------- weight pack
// s=0..2: Wc thirds (Wc = w_ih @ conv_w^T); s=3..5: w_hh thirds; s=6: w2
__global__ void k_packW(const float* __restrict__ w_ih, const float* __restrict__ conv_w,
                        const float* __restrict__ w_hh, const float* __restrict__ w2,
                        short8* __restrict__ Whi, short8* __restrict__ Wlo) {
  int gid = blockIdx.x * 256 + threadIdx.x;
  if (gid >= 7 * 7 * 4 * 64) return;
  int lane = gid & 63;
  int kt = (gid >> 6) & 3;
  int snt = gid >> 8;
  int nt = snt % 7;
  int s = snt / 7;
  int d = nt * 16 + (lane & 15);
  int k0 = kt * 32 + (lane >> 4) * 8;
  short8 h, l;
#pragma unroll
  for (int j = 0; j < 8; ++j) {
    int k = k0 + j;
    float v = 0.f;
    if (d < 100 && k < 100) {
      if (s < 3) {
        const float* wr = w_ih + (size_t)(s * 100 + d) * 100;
        const float* cr = conv_w + (size_t)k * 100;
        float acc = 0.f;
        for (int t = 0; t < 100; ++t) acc = fmaf(wr[t], cr[t], acc);
        v = acc;
      } else if (s < 6) {
        v = w_hh[(size_t)((s - 3) * 100 + d) * 100 + k];
      } else {
        v = w2[(size_t)d * 100 + k];
      }
    }
    short hh, ll;
    bf16split(v, hh, ll);
    h[j] = hh; l[j] = ll;
  }
  Whi[gid] = h;
  Wlo[gid] = l;
}

// load + convert A fragments for one 16-row m-tile (K=100, padded to 128)
__device__ __forceinline__ void load_afrags(const float* __restrict__ A, int rowBase,
                                            int lane, short8 ah[4], short8 al[4]) {
  int r = rowBase + (lane & 15);
  int g = lane >> 4;
#pragma unroll
  for (int kt = 0; kt < 4; ++kt) {
    int k0 = kt * 32 + g * 8;
    float4 f0 = make_float4(0.f, 0.f, 0.f, 0.f);
    float4 f1 = make_float4(0.f, 0.f, 0.f, 0.f);
    if (k0 < 100)     f0 = *(const float4*)(A + (size_t)r * DDIM + k0);
    if (k0 + 4 < 100) f1 = *(const float4*)(A + (size_t)r * DDIM + k0 + 4);
    float v[8] = {f0.x, f0.y, f0.z, f0.w, f1.x, f1.y, f1.z, f1.w};
    short8 h, l;
#pragma unroll
    for (int j = 0; j < 8; ++j) {
      short hh, ll;
      bf16split(v[j], hh, ll);
      h[j] = hh; l[j] = ll;
    }
    ah[kt] = h; al[kt] = l;
  }
}

// ---------------------------------------------------------------- fused GGC+GRU
__global__ __launch_bounds__(256) void k_grufused(
    const float* __restrict__ aggH, const float* __restrict__ h0,
    const short8* __restrict__ Whi, const short8* __restrict__ Wlo,
    const float* __restrict__ b_ih, const float* __restrict__ b_hh,
    float* __restrict__ xh) {
  const int lane = threadIdx.x & 63;
  const int wave = threadIdx.x >> 6;
  const int rowBase = blockIdx.x * 64 + wave * 16;
  short8 aIh[4], aIl[4], aHh[4], aHl[4];
  load_afrags(aggH, rowBase, lane, aIh, aIl);
  load_afrags(h0, rowBase, lane, aHh, aHl);
  const int c0 = lane & 15;
  const int r0 = (lane >> 4) * 4;

  for (int nt = 0; nt < 7; ++nt) {
    int d = nt * 16 + c0;
    f32x4 acc[6];
#pragma unroll
    for (int s = 0; s < 6; ++s) {
      f32x4 a = {0.f, 0.f, 0.f, 0.f};
#pragma unroll
      for (int kt = 0; kt < 4; ++kt) {
        size_t off = (((size_t)s * 7 + nt) * 4 + kt) * 64 + lane;
        short8 bh = Whi[off];
        short8 bl = Wlo[off];
        if (s < 3) {
          a = mfma16(aIh[kt], bh, a);
          a = mfma16(aIh[kt], bl, a);
          a = mfma16(aIl[kt], bh, a);
        } else {
          a = mfma16(aHh[kt], bh, a);
          a = mfma16(aHh[kt], bl, a);
          a = mfma16(aHl[kt], bh, a);
        }
      }
      acc[s] = a;
    }
    if (d < 100) {
      float bir = b_ih[d], biz = b_ih[100 + d], bin_ = b_ih[200 + d];
      float bhr = b_hh[d], bhz = b_hh[100 + d], bhn = b_hh[200 + d];
#pragma unroll
      for (int ri = 0; ri < 4; ++ri) {
        int row = rowBase + r0 + ri;
        float r = sigm(acc[0][ri] + bir + acc[3][ri] + bhr);
        float z = sigm(acc[1][ri] + biz + acc[4][ri] + bhz);
        float n = tanhf(acc[2][ri] + bin_ + r * (acc[5][ri] + bhn));
        float h0v = h0[(size_t)row * DDIM + d];
        float v = (1.f - z) * n + z * h0v;
        xh[(size_t)row * DDIM + d] = v > 0.f ? v : 0.f;
      }
    }
  }
}

// t2 = A @ w2^T + b2  (Nout=100) via MFMA, W frags = set 6
__global__ __launch_bounds__(256) void k_mm100(
    const float* __restrict__ A, const short8* __restrict__ Whi,
    const short8* __restrict__ Wlo, const float* __restrict__ bias,
    float* __restrict__ out) {
  const int lane = threadIdx.x & 63;
  const int wave = threadIdx.x >> 6;
  const int rowBase = blockIdx.x * 64 + wave * 16;
  short8 ah[4], al[4];
  load_afrags(A, rowBase, lane, ah, al);
  const int c0 = lane & 15;
  const int r0 = (lane >> 4) * 4;

  for (int nt = 0; nt < 7; ++nt) {
    int d = nt * 16 + c0;
    f32x4 a = {0.f, 0.f, 0.f, 0.f};
#pragma unroll
    for (int kt = 0; kt < 4; ++kt) {
      size_t off = (((size_t)6 * 7 + nt) * 4 + kt) * 64 + lane;
      short8 bh = Whi[off];
      short8 bl = Wlo[off];
      a = mfma16(ah[kt], bh, a);
      a = mfma16(ah[kt], bl, a);
      a = mfma16(al[kt], bh, a);
    }
    if (d < 100) {
      float b = bias[d];
#pragma unroll
      for (int ri = 0; ri < 4; ++ri) {
        int row = rowBase + r0 + ri;
        out[(size_t)row * DDIM + d] = a[ri] + b;
      }
    }
  }
}

// ---------------------------------------------------------------- big MFMA GEMM
// out = S @ emb^T, packed bf16 hi/lo, split-precision. B staged per-BLOCK in a
// PFD-deep LDS ring via global_load_lds; counted vmcnt (never 0) keeps 3 slots
// + stores in flight across raw s_barriers (T3/T4 pattern).
__global__ __launch_bounds__(256) void k_bigmm(
    const short8* __restrict__ Ahi, const short8* __restrict__ Alo,
    const short8* __restrict__ Bhi, const short8* __restrict__ Blo,
    float* __restrict__ out, int NT, int NTCHUNK, int NCOLS) {
  __shared__ short8 Bs[PFD * 8 * 64];  // 4 slots x 8KB
  const int lane = threadIdx.x & 63;
  const int wave = threadIdx.x >> 6;
  const int mt0 = blockIdx.y * 8 + wave * 2;

  short8 ah[2][4], al[2][4];
#pragma unroll
  for (int mi = 0; mi < 2; ++mi)
#pragma unroll
    for (int kt = 0; kt < 4; ++kt) {
      size_t off = ((size_t)(mt0 + mi) * 4 + kt) * 64 + lane;
      ah[mi][kt] = Ahi[off];
      al[mi][kt] = Alo[off];
    }

  const int nt0 = blockIdx.x * NTCHUNK;
  const int nt1 = min(NT, nt0 + NTCHUNK);
  const int r0 = (lane >> 4) * 4;
  const int c0 = lane & 15;

  // wave w stages pieces {w (hi,kt=w), 4+w (lo,kt=w)} of each slot
  auto issueB = [&](int nt) {
    int s = nt & (PFD - 1);
    gld_lds16(Bhi + ((size_t)nt * 4 + wave) * 64 + lane, &Bs[(s * 8 + wave) * 64]);
    gld_lds16(Blo + ((size_t)nt * 4 + wave) * 64 + lane, &Bs[(s * 8 + 4 + wave) * 64]);
  };

  // prologue: fill ring
  for (int i = 0; i < PFD && nt0 + i < nt1; ++i) issueB(nt0 + i);
  asm volatile("s_waitcnt vmcnt(6)" ::: "memory");  // first slot (and A) ready for this wave
  __builtin_amdgcn_s_barrier();                      // ready for all waves

  for (int nt = nt0; nt < nt1; ++nt) {
    const int s = nt & (PFD - 1);
    // slot -> regs
    short8 bh[4], bl[4];
#pragma unroll
    for (int kt = 0; kt < 4; ++kt) {
      bh[kt] = Bs[(s * 8 + kt) * 64 + lane];
      bl[kt] = Bs[(s * 8 + 4 + kt) * 64 + lane];
    }
    asm volatile("s_waitcnt lgkmcnt(0)" ::: "memory");  // my reads complete
    __builtin_amdgcn_s_barrier();                        // all waves done with slot s
    if (nt + PFD < nt1) issueB(nt + PFD);                // refill slot s
    __builtin_amdgcn_sched_barrier(0);

    f32x4 acc0 = {0.f, 0.f, 0.f, 0.f};
    f32x4 acc1 = {0.f, 0.f, 0.f, 0.f};
#pragma unroll
    for (int kt = 0; kt < 4; ++kt) {
      acc0 = mfma16(ah[0][kt], bh[kt], acc0);
      acc1 = mfma16(ah[1][kt], bh[kt], acc1);
      acc0 = mfma16(ah[0][kt], bl[kt], acc0);
      acc1 = mfma16(ah[1][kt], bl[kt], acc1);
      acc0 = mfma16(al[0][kt], bh[kt], acc0);
      acc1 = mfma16(al[1][kt], bh[kt], acc1);
    }
    int col = nt * 16 + c0;
    if (col < NCOLS) {
#pragma unroll
      for (int r = 0; r < 4; ++r) {
        __builtin_nontemporal_store(acc0[r], out + (size_t)(mt0 * 16 + r0 + r) * NCOLS + col);
        __builtin_nontemporal_store(acc1[r], out + (size_t)((mt0 + 1) * 16 + r0 + r) * NCOLS + col);
      }
    }
    // next slot's loads done for this wave (valid: >=14 ops issued after them)
    asm volatile("s_waitcnt vmcnt(14)" ::: "memory");
    __builtin_amdgcn_s_barrier();
  }
}

// ---------------------------------------------------------------- launcher

extern "C" void kernel_launch(void* const* d_in, const int* in_sizes, int n_in,
                              void* d_out, int out_size, void* d_ws, size_t ws_size,
                              hipStream_t stream) {
  const int*   x      = (const int*)d_in[0];
  const int*   ei     = (const int*)d_in[1];
  const int*   batch  = (const int*)d_in[2];
  const float* emb    = (const float*)d_in[4];
  const float* conv_w = (const float*)d_in[5];
  const float* w_ih   = (const float*)d_in[6];
  const float* w_hh   = (const float*)d_in[7];
  const float* b_ih   = (const float*)d_in[8];
  const float* b_hh   = (const float*)d_in[9];
  const float* q_w    = (const float*)d_in[10];
  const float* q_b    = (const float*)d_in[11];
  const float* w2     = (const float*)d_in[12];
  const float* b2     = (const float*)d_in[13];
  const float* w3     = (const float*)d_in[14];
  const float* b3     = (const float*)d_in[15];
  const float* w4     = (const float*)d_in[16];
  const float* b4     = (const float*)d_in[17];

  const int N = in_sizes[0];            // 49152
  const int E = in_sizes[1] / 2;        // 98304
  const int NNODE = in_sizes[4] / DDIM; // 50000
  const int B = out_size / NNODE;       // 4096

  size_t ND = (size_t)N * DDIM;
  float* ws   = (float*)d_ws;
  float* h0   = ws;            // [N,100]
  float* aggH = ws + ND;       // [N,100]
  float* xh   = ws + 2 * ND;   // [N,100]
  float* t2   = ws + 3 * ND;   // [N,100]
  float* aux  = ws + 4 * ND;
  float* t3v  = aux;                           // [B,100]
  float* Scat = t3v + (size_t)B * DDIM;        // [B,300]
  float* Sm   = Scat + 3 * (size_t)B * DDIM;   // [B,100]
  int*   lastI = (int*)(Sm + (size_t)B * DDIM);// [B]

  const int MT = (B + 15) / 16;          // 256
  const int NT = (NNODE + 15) / 16;      // 3125
  short8* Whi = (short8*)(lastI + B);    // 7 sets x [7][4][64]
  short8* Wlo = Whi + 7 * 7 * 4 * 64;
  short8* Ahi = Wlo + 7 * 7 * 4 * 64;
  short8* Alo = Ahi + (size_t)MT * 4 * 64;
  short8* Bhi = Alo + (size_t)MT * 4 * 64;
  short8* Blo = Bhi + (size_t)NT * 4 * 64;

  dim3 blk(256);
  int gyB = (B + 127) / 128;  // 32

  // independent prep
  k_pack<<<(NT * 4 * 64 + 255) / 256, blk, 0, stream>>>(emb, Bhi, Blo, NNODE, NT);
  k_packW<<<(7 * 7 * 4 * 64 + 255) / 256, blk, 0, stream>>>(w_ih, conv_w, w_hh, w2, Whi, Wlo);

  // node chain
  k_gather4<<<(N * 25 + 255) / 256, blk, 0, stream>>>(x, emb, (float4*)h0, (float4*)aggH,
                                                      batch, lastI, N);
  k_scatter<<<(E * 25 + 255) / 256, blk, 0, stream>>>(ei, h0, aggH, E);
  k_grufused<<<N / 64, blk, 0, stream>>>(aggH, h0, Whi, Wlo, b_ih, b_hh, xh);
  k_mm100<<<N / 64, blk, 0, stream>>>(xh, Whi, Wlo, b2, t2);
  // t3v = v_n @ w3^T + b3, gathering v_n rows from xh via lastI
  gemm_abt<100, 1><<<dim3(2, gyB), blk, 0, stream>>>(xh, w3, b3, t3v, lastI, B, DDIM);
  k_session<<<(B + 3) / 4, blk, 0, stream>>>(xh, t2, t3v, q_w, q_b, lastI, Scat, B);
  gemm_abt<300, 1><<<dim3(2, gyB), blk, 0, stream>>>(Scat, w4, b4, Sm, nullptr, B, DDIM);

  // final big GEMM
  k_pack<<<(MT * 4 * 64 + 255) / 256, blk, 0, stream>>>(Sm, Ahi, Alo, B, MT);
  const int NCHUNKS = 64;
  const int NTCHUNK = (NT + NCHUNKS - 1) / NCHUNKS;  // 49
  k_bigmm<<<dim3(NCHUNKS, (B + 127) / 128), blk, 0, stream>>>(
      Ahi, Alo, Bhi, Blo, (float*)d_out, NT, NTCHUNK, NNODE);
}

// Round 6
// 511.551 us; speedup vs baseline: 2.6307x; 1.1807x over previous
//
#include <hip/hip_runtime.h>
#include <math.h>

#define DDIM 100   // embed dim
#define PFD  4     // k_bigmm LDS ring depth
#define NTG  4     // k_bigmm n-tiles per store group (64 cols -> 256B/row stores)

using short8 = __attribute__((ext_vector_type(8))) short;
using f32x4  = __attribute__((ext_vector_type(4))) float;

// ---------------------------------------------------------------- utilities

__device__ __forceinline__ float wave_sum64(float v) {
#pragma unroll
  for (int o = 32; o > 0; o >>= 1) v += __shfl_xor(v, o, 64);
  return v;
}

__device__ __forceinline__ float sigm(float x) { return 1.f / (1.f + expf(-x)); }

__device__ __forceinline__ f32x4 mfma16(short8 a, short8 b, f32x4 c) {
  return __builtin_amdgcn_mfma_f32_16x16x32_bf16(a, b, c, 0, 0, 0);
}

__device__ __forceinline__ void gld_lds16(const void* g, void* l) {
  __builtin_amdgcn_global_load_lds(
      (const __attribute__((address_space(1))) void*)g,
      (__attribute__((address_space(3))) void*)l, 16, 0, 0);
}

// RNE bf16 split: v ~= hi + lo
__device__ __forceinline__ void bf16split(float v, short& h, short& l) {
  unsigned u = __float_as_uint(v);
  unsigned hb = (u + 0x7fffu + ((u >> 16) & 1u)) & 0xffff0000u;
  float res = v - __uint_as_float(hb);
  unsigned u2 = __float_as_uint(res);
  h = (short)(hb >> 16);
  l = (short)((u2 + 0x7fffu + ((u2 >> 16) & 1u)) >> 16);
}

__device__ __forceinline__ short bf16hi(float v) {
  unsigned u = __float_as_uint(v);
  return (short)((u + 0x7fffu + ((u >> 16) & 1u)) >> 16);
}

// ---------------------------------------------------------------- elementwise

// h0 = emb[x-1], aggH = 0, last-node-per-session
__global__ void k_gather4(const int* __restrict__ x, const float* __restrict__ emb,
                          float4* __restrict__ h0, float4* __restrict__ aggH,
                          const int* __restrict__ batch, int* __restrict__ last_idx,
                          int n) {
  int i = blockIdx.x * 256 + threadIdx.x;
  if (i < n * 25) {
    int node = i / 25, c = i - node * 25;
    h0[i] = *(const float4*)(emb + (size_t)(x[node] - 1) * DDIM + 4 * c);
    aggH[i] = make_float4(0.f, 0.f, 0.f, 0.f);
  }
  if (i < n) {
    if (i == n - 1 || batch[i + 1] != batch[i]) last_idx[batch[i]] = i;
  }
}

// aggH[dst] += h0[src]
__global__ void k_scatter(const int* __restrict__ ei, const float* __restrict__ src_rows,
                          float* __restrict__ aggH, int E) {
  int i = blockIdx.x * 256 + threadIdx.x;
  if (i < E * 25) {
    int e = i / 25, c = i - e * 25;
    int s = ei[e], d = ei[E + e];
    float4 v = *(const float4*)(src_rows + (size_t)s * DDIM + 4 * c);
    float* ap = aggH + (size_t)d * DDIM + 4 * c;
    atomicAdd(ap + 0, v.x); atomicAdd(ap + 1, v.y);
    atomicAdd(ap + 2, v.z); atomicAdd(ap + 3, v.w);
  }
}

// one wave per session: one-pass online softmax pooling (S_s), gated pooling (S_g), v_n
__global__ __launch_bounds__(256) void k_session(
    const float* __restrict__ xh, const float* __restrict__ t2,
    const float* __restrict__ t3v,
    const float* __restrict__ q_w, const float* __restrict__ q_b,
    const int* __restrict__ last_idx, float* __restrict__ Scat, int B) {
  int sid = blockIdx.x * 4 + (threadIdx.x >> 6);
  if (sid >= B) return;
  int lane = threadIdx.x & 63;
  bool hi = lane < (DDIM - 64);  // 36
  int start = (sid == 0) ? 0 : last_idx[sid - 1] + 1;
  int end = last_idx[sid];

  float v0 = xh[(size_t)end * DDIM + lane];
  float v1 = hi ? xh[(size_t)end * DDIM + 64 + lane] : 0.f;
  float t30 = t3v[(size_t)sid * DDIM + lane];
  float t31 = hi ? t3v[(size_t)sid * DDIM + 64 + lane] : 0.f;
  float q0 = q_w[lane];
  float q1 = hi ? q_w[64 + lane] : 0.f;
  float qb = q_b[0];

  float m = -INFINITY, denom = 0.f;
  float ss0 = 0.f, ss1 = 0.f, sg0 = 0.f, sg1 = 0.f;
  for (int i = start; i <= end; ++i) {
    float x0 = xh[(size_t)i * DDIM + lane];
    float x1 = hi ? xh[(size_t)i * DDIM + 64 + lane] : 0.f;
    float l = wave_sum64(x0 * v0 + x1 * v1);
    float mn = fmaxf(m, l);
    float cf = expf(m - mn);
    float p = expf(l - mn);
    denom = denom * cf + p;
    ss0 = ss0 * cf + p * x0;
    ss1 = ss1 * cf + p * x1;
    m = mn;
    float g0 = sigm(t2[(size_t)i * DDIM + lane] + t30);
    float g1 = hi ? sigm(t2[(size_t)i * DDIM + 64 + lane] + t31) : 0.f;
    float alpha = wave_sum64(q0 * g0 + q1 * g1) + qb;
    sg0 += alpha * x0; sg1 += alpha * x1;
  }
  float inv = 1.f / denom;
  float* Sc = Scat + (size_t)sid * 300;
  Sc[lane] = ss0 * inv;       if (hi) Sc[64 + lane] = ss1 * inv;
  Sc[100 + lane] = sg0;       if (hi) Sc[164 + lane] = sg1;
  Sc[200 + lane] = v0;        if (hi) Sc[264 + lane] = v1;
}

// ---------------------------------------------------------------- combined pack
// part 1: emb -> Bhi/Blo fragments (hi/lo split)
// part 2: weights -> Whi (hi only), 8 sets: 0..2 Wc=w_ih@conv_w^T thirds,
//         3..5 w_hh thirds, 6 w2, 7 w3
__global__ void k_packAll(const float* __restrict__ emb,
                          const float* __restrict__ w_ih, const float* __restrict__ conv_w,
                          const float* __restrict__ w_hh, const float* __restrict__ w2,
                          const float* __restrict__ w3,
                          short8* __restrict__ Bhi, short8* __restrict__ Blo,
                          short8* __restrict__ Whi, int NNODE, int NT) {
  int gid = blockIdx.x * 256 + threadIdx.x;
  int embN = NT * 4 * 64;
  if (gid < embN) {
    int lane = gid & 63;
    int kt = (gid >> 6) & 3;
    int rt = gid >> 8;
    int r = rt * 16 + (lane & 15);
    if (r >= NNODE) r = NNODE - 1;
    int kb = kt * 32 + (lane >> 4) * 8;
    short8 h, l;
#pragma unroll
    for (int j = 0; j < 8; ++j) {
      int k = kb + j;
      float v = (k < DDIM) ? emb[(size_t)r * DDIM + k] : 0.f;
      short hh, ll;
      bf16split(v, hh, ll);
      h[j] = hh; l[j] = ll;
    }
    Bhi[gid] = h;
    Blo[gid] = l;
  } else {
    int wg = gid - embN;
    if (wg >= 8 * 7 * 4 * 64) return;
    int lane = wg & 63;
    int kt = (wg >> 6) & 3;
    int snt = wg >> 8;
    int nt = snt % 7;
    int s = snt / 7;
    int d = nt * 16 + (lane & 15);
    int k0 = kt * 32 + (lane >> 4) * 8;
    short8 h;
#pragma unroll
    for (int j = 0; j < 8; ++j) {
      int k = k0 + j;
      float v = 0.f;
      if (d < 100 && k < 100) {
        if (s < 3) {
          const float* wr = w_ih + (size_t)(s * 100 + d) * 100;
          const float* cr = conv_w + (size_t)k * 100;
          float acc = 0.f;
          for (int t = 0; t < 100; ++t) acc = fmaf(wr[t], cr[t], acc);
          v = acc;
        } else if (s < 6) {
          v = w_hh[(size_t)((s - 3) * 100 + d) * 100 + k];
        } else if (s == 6) {
          v = w2[(size_t)d * 100 + k];
        } else {
          v = w3[(size_t)d * 100 + k];
        }
      }
      h[j] = bf16hi(v);
    }
    Whi[wg] = h;
  }
}

// hi-only A fragment loads for one 16-row m-tile (K=100 padded to 128)
__device__ __forceinline__ void load_afragsH(const float* __restrict__ A, int rowBase,
                                             int lane, short8 ah[4]) {
  int r = rowBase + (lane & 15);
  int g = lane >> 4;
#pragma unroll
  for (int kt = 0; kt < 4; ++kt) {
    int k0 = kt * 32 + g * 8;
    float4 f0 = make_float4(0.f, 0.f, 0.f, 0.f);
    float4 f1 = make_float4(0.f, 0.f, 0.f, 0.f);
    if (k0 < 100)     f0 = *(const float4*)(A + (size_t)r * DDIM + k0);
    if (k0 + 4 < 100) f1 = *(const float4*)(A + (size_t)r * DDIM + k0 + 4);
    short8 h;
    h[0] = bf16hi(f0.x); h[1] = bf16hi(f0.y); h[2] = bf16hi(f0.z); h[3] = bf16hi(f0.w);
    h[4] = bf16hi(f1.x); h[5] = bf16hi(f1.y); h[6] = bf16hi(f1.z); h[7] = bf16hi(f1.w);
    ah[kt] = h;
  }
}

__device__ __forceinline__ void load_afragsHg(const float* __restrict__ A,
                                              const int* __restrict__ idx, int base,
                                              int lane, short8 ah[4]) {
  int r = idx[base + (lane & 15)];
  int g = lane >> 4;
#pragma unroll
  for (int kt = 0; kt < 4; ++kt) {
    int k0 = kt * 32 + g * 8;
    float4 f0 = make_float4(0.f, 0.f, 0.f, 0.f);
    float4 f1 = make_float4(0.f, 0.f, 0.f, 0.f);
    if (k0 < 100)     f0 = *(const float4*)(A + (size_t)r * DDIM + k0);
    if (k0 + 4 < 100) f1 = *(const float4*)(A + (size_t)r * DDIM + k0 + 4);
    short8 h;
    h[0] = bf16hi(f0.x); h[1] = bf16hi(f0.y); h[2] = bf16hi(f0.z); h[3] = bf16hi(f0.w);
    h[4] = bf16hi(f1.x); h[5] = bf16hi(f1.y); h[6] = bf16hi(f1.z); h[7] = bf16hi(f1.w);
    ah[kt] = h;
  }
}

// ---------------------------------------------------------------- fused GGC+GRU
// 2 m-tiles (32 rows) per wave; hi-only bf16 (error ~1e-4 on xh, negligible)
__global__ __launch_bounds__(256) void k_grufused(
    const float* __restrict__ aggH, const float* __restrict__ h0,
    const short8* __restrict__ Whi,
    const float* __restrict__ b_ih, const float* __restrict__ b_hh,
    float* __restrict__ xh) {
  const int lane = threadIdx.x & 63;
  const int wave = threadIdx.x >> 6;
  const int rowBase = blockIdx.x * 128 + wave * 32;
  short8 aI0[4], aI1[4], aH0[4], aH1[4];
  load_afragsH(aggH, rowBase, lane, aI0);
  load_afragsH(aggH, rowBase + 16, lane, aI1);
  load_afragsH(h0, rowBase, lane, aH0);
  load_afragsH(h0, rowBase + 16, lane, aH1);
  const int c0 = lane & 15;
  const int r0 = (lane >> 4) * 4;

  for (int nt = 0; nt < 7; ++nt) {
    int d = nt * 16 + c0;
    f32x4 a0[6] = {};
    f32x4 a1[6] = {};
#pragma unroll
    for (int s = 0; s < 6; ++s) {
#pragma unroll
      for (int kt = 0; kt < 4; ++kt) {
        short8 w = Whi[(((size_t)s * 7 + nt) * 4 + kt) * 64 + lane];
        if (s < 3) {
          a0[s] = mfma16(aI0[kt], w, a0[s]);
          a1[s] = mfma16(aI1[kt], w, a1[s]);
        } else {
          a0[s] = mfma16(aH0[kt], w, a0[s]);
          a1[s] = mfma16(aH1[kt], w, a1[s]);
        }
      }
    }
    if (d < 100) {
      float bir = b_ih[d], biz = b_ih[100 + d], bin_ = b_ih[200 + d];
      float bhr = b_hh[d], bhz = b_hh[100 + d], bhn = b_hh[200 + d];
#pragma unroll
      for (int ri = 0; ri < 4; ++ri) {
        {
          int row = rowBase + r0 + ri;
          float r = sigm(a0[0][ri] + bir + a0[3][ri] + bhr);
          float z = sigm(a0[1][ri] + biz + a0[4][ri] + bhz);
          float n = tanhf(a0[2][ri] + bin_ + r * (a0[5][ri] + bhn));
          float h0v = h0[(size_t)row * DDIM + d];
          float v = (1.f - z) * n + z * h0v;
          xh[(size_t)row * DDIM + d] = v > 0.f ? v : 0.f;
        }
        {
          int row = rowBase + 16 + r0 + ri;
          float r = sigm(a1[0][ri] + bir + a1[3][ri] + bhr);
          float z = sigm(a1[1][ri] + biz + a1[4][ri] + bhz);
          float n = tanhf(a1[2][ri] + bin_ + r * (a1[5][ri] + bhn));
          float h0v = h0[(size_t)row * DDIM + d];
          float v = (1.f - z) * n + z * h0v;
          xh[(size_t)row * DDIM + d] = v > 0.f ? v : 0.f;
        }
      }
    }
  }
}

// t2 = xh @ w2^T + b2 (blocks < nblkA) ; t3v = xh[lastI] @ w3^T + b3 (rest)
__global__ __launch_bounds__(256) void k_mm100t3(
    const float* __restrict__ xh, const short8* __restrict__ Whi,
    const float* __restrict__ b2, const float* __restrict__ b3,
    const int* __restrict__ lastI,
    float* __restrict__ t2, float* __restrict__ t3v, int nblkA) {
  const int bb = blockIdx.x;
  const int lane = threadIdx.x & 63;
  const int wave = threadIdx.x >> 6;
  const bool isT3 = bb >= nblkA;
  const int setIdx = isT3 ? 7 : 6;
  const float* bias = isT3 ? b3 : b2;
  float* out = isT3 ? t3v : t2;
  const int rowBase = (isT3 ? (bb - nblkA) : bb) * 128 + wave * 32;

  short8 a0[4], a1[4];
  if (isT3) {
    load_afragsHg(xh, lastI, rowBase, lane, a0);
    load_afragsHg(xh, lastI, rowBase + 16, lane, a1);
  } else {
    load_afragsH(xh, rowBase, lane, a0);
    load_afragsH(xh, rowBase + 16, lane, a1);
  }
  const int c0 = lane & 15;
  const int r0 = (lane >> 4) * 4;

  for (int nt = 0; nt < 7; ++nt) {
    int d = nt * 16 + c0;
    f32x4 ac0 = {0.f, 0.f, 0.f, 0.f};
    f32x4 ac1 = {0.f, 0.f, 0.f, 0.f};
#pragma unroll
    for (int kt = 0; kt < 4; ++kt) {
      short8 w = Whi[(((size_t)setIdx * 7 + nt) * 4 + kt) * 64 + lane];
      ac0 = mfma16(a0[kt], w, ac0);
      ac1 = mfma16(a1[kt], w, ac1);
    }
    if (d < 100) {
      float b = bias[d];
#pragma unroll
      for (int ri = 0; ri < 4; ++ri) {
        out[(size_t)(rowBase + r0 + ri) * DDIM + d] = ac0[ri] + b;
        out[(size_t)(rowBase + 16 + r0 + ri) * DDIM + d] = ac1[ri] + b;
      }
    }
  }
}

// ---------------------------------------------------------------- S GEMM -> packed frags
// S = Scat @ w4^T + b4, written DIRECTLY as hi/lo bf16 A-fragments for k_bigmm.
__global__ __launch_bounds__(256, 2) void k_gemmS(
    const float* __restrict__ A, const float* __restrict__ Bm,
    const float* __restrict__ bias, short* __restrict__ Ph, short* __restrict__ Pl,
    int M) {
  __shared__ float4 As4[25 * 128];  // 51.2 KB
  __shared__ float4 Bs4[25 * 64];   // 25.6 KB
  const int m0 = blockIdx.y * 128;
  const int n0 = blockIdx.x * 64;
  const int t = threadIdx.x;
  const int tx = t & 15;
  const int ty = t >> 4;
  float acc[8][4] = {};

  for (int kt = 0; kt < 300; kt += 100) {
    for (int idx = t; idx < 128 * 25; idx += 256) {
      int r = idx / 25, k4 = idx - r * 25;
      int ar = m0 + r; if (ar >= M) ar = M - 1;
      float4 v = *(const float4*)(A + (size_t)ar * 300 + kt + 4 * k4);
      As4[k4 * 128 + (r ^ (k4 & 7))] = v;
    }
    for (int idx = t; idx < 64 * 25; idx += 256) {
      int r = idx / 25, k4 = idx - r * 25;
      int br = n0 + r;
      float4 v = make_float4(0.f, 0.f, 0.f, 0.f);
      if (br < 100) v = *(const float4*)(Bm + (size_t)br * 300 + kt + 4 * k4);
      Bs4[k4 * 64 + (r ^ (k4 & 7))] = v;
    }
    __syncthreads();
#pragma unroll 5
    for (int k4 = 0; k4 < 25; ++k4) {
      const int s = k4 & 7;
      float4 av[8], bv[4];
#pragma unroll
      for (int i = 0; i < 8; ++i) av[i] = As4[k4 * 128 + ((ty + 16 * i) ^ s)];
#pragma unroll
      for (int j = 0; j < 4; ++j) bv[j] = Bs4[k4 * 64 + ((tx + 16 * j) ^ s)];
#pragma unroll
      for (int i = 0; i < 8; ++i) {
#pragma unroll
        for (int j = 0; j < 4; ++j) {
          acc[i][j] = fmaf(av[i].x, bv[j].x, acc[i][j]);
          acc[i][j] = fmaf(av[i].y, bv[j].y, acc[i][j]);
          acc[i][j] = fmaf(av[i].z, bv[j].z, acc[i][j]);
          acc[i][j] = fmaf(av[i].w, bv[j].w, acc[i][j]);
        }
      }
    }
    __syncthreads();
  }

#pragma unroll
  for (int i = 0; i < 8; ++i) {
    int row = m0 + ty + 16 * i;
    if (row >= M) continue;
#pragma unroll
    for (int j = 0; j < 4; ++j) {
      int col = n0 + tx + 16 * j;   // 0..127 (>=100 -> zero pad slot)
      float v = (col < 100) ? (acc[i][j] + bias[col]) : 0.f;
      short hh, ll;
      bf16split(v, hh, ll);
      int rt = row >> 4, kt = col >> 5;
      int lane_t = (row & 15) + 16 * ((col >> 3) & 3);
      size_t base = ((((size_t)rt * 4 + kt) * 64 + lane_t) << 3) + (col & 7);
      Ph[base] = hh;
      Pl[base] = ll;
    }
  }
}

// ---------------------------------------------------------------- big MFMA GEMM
// out = S @ emb^T. B staged per-block in PFD-deep LDS ring (counted vmcnt).
// NTG n-tiles accumulated per group, then wave-private LDS transpose ->
// 256B-contiguous dwordx4 stores (vs 64B scattered before).
__global__ __launch_bounds__(256) void k_bigmm(
    const short8* __restrict__ Ahi, const short8* __restrict__ Alo,
    const short8* __restrict__ Bhi, const short8* __restrict__ Blo,
    float* __restrict__ out, int NT, int NTCHUNK, int NCOLS) {
  __shared__ short8 Bs[PFD * 8 * 64];   // 32 KB ring
  __shared__ float Xp[4 * 32 * 64];     // 32 KB transpose stripes (8KB/wave)
  const int lane = threadIdx.x & 63;
  const int wave = threadIdx.x >> 6;
  const int mt0 = blockIdx.x * 8 + wave * 2;   // rows on X; col-chunks on Y (L2 locality)

  short8 ah[2][4], al[2][4];
#pragma unroll
  for (int mi = 0; mi < 2; ++mi)
#pragma unroll
    for (int kt = 0; kt < 4; ++kt) {
      size_t off = ((size_t)(mt0 + mi) * 4 + kt) * 64 + lane;
      ah[mi][kt] = Ahi[off];
      al[mi][kt] = Alo[off];
    }

  const int nt0 = blockIdx.y * NTCHUNK;
  const int nt1 = min(NT, nt0 + NTCHUNK);
  const int r0 = (lane >> 4) * 4;
  const int c0 = lane & 15;
  float* xp = &Xp[wave * 32 * 64];

  auto issueB = [&](int nt) {
    int s = nt & (PFD - 1);
    gld_lds16(Bhi + ((size_t)nt * 4 + wave) * 64 + lane, &Bs[(s * 8 + wave) * 64]);
    gld_lds16(Blo + ((size_t)nt * 4 + wave) * 64 + lane, &Bs[(s * 8 + 4 + wave) * 64]);
  };

  // prologue (nt1-nt0 >= 4 always given NTCHUNK=48, NT=3125)
  for (int i = 0; i < PFD && nt0 + i < nt1; ++i) issueB(nt0 + i);
  asm volatile("s_waitcnt vmcnt(6)" ::: "memory");
  __builtin_amdgcn_s_barrier();

  for (int g = nt0; g < nt1; g += NTG) {
    const int jn = min(NTG, nt1 - g);   // block-uniform
    f32x4 acc[2][NTG] = {};
#pragma unroll
    for (int j = 0; j < NTG; ++j) {
      if (j >= jn) break;
      const int nt = g + j;
      const int s = nt & (PFD - 1);
      short8 bh[4], bl[4];
#pragma unroll
      for (int kt = 0; kt < 4; ++kt) {
        bh[kt] = Bs[(s * 8 + kt) * 64 + lane];
        bl[kt] = Bs[(s * 8 + 4 + kt) * 64 + lane];
      }
      asm volatile("s_waitcnt lgkmcnt(0)" ::: "memory");
      __builtin_amdgcn_s_barrier();
      if (nt + PFD < nt1) issueB(nt + PFD);
      __builtin_amdgcn_sched_barrier(0);
#pragma unroll
      for (int kt = 0; kt < 4; ++kt) {
        acc[0][j] = mfma16(ah[0][kt], bh[kt], acc[0][j]);
        acc[1][j] = mfma16(ah[1][kt], bh[kt], acc[1][j]);
        acc[0][j] = mfma16(ah[0][kt], bl[kt], acc[0][j]);
        acc[1][j] = mfma16(ah[1][kt], bl[kt], acc[1][j]);
        acc[0][j] = mfma16(al[0][kt], bh[kt], acc[0][j]);
        acc[1][j] = mfma16(al[1][kt], bh[kt], acc[1][j]);
      }
      // slot for next iter landed: newer ops <= 6 loads + 8 stores = 14
      asm volatile("s_waitcnt vmcnt(14)" ::: "memory");
      __builtin_amdgcn_s_barrier();
    }
    // wave-private transpose: acc -> 32x64 stripe (XOR-swizzled, 2-way max)
#pragma unroll
    for (int mi = 0; mi < 2; ++mi)
#pragma unroll
      for (int j = 0; j < NTG; ++j) {
        if (j < jn) {
#pragma unroll
          for (int r = 0; r < 4; ++r) {
            int rl = mi * 16 + r0 + r;
            int cl = j * 16 + c0;
            xp[rl * 64 + (cl ^ (((rl >> 2) & 3) << 4))] = acc[mi][j][r];
          }
        }
      }
    // read back 4 consecutive cols/lane -> 256B-contiguous row segments
    const int colbase = g * 16;
#pragma unroll
    for (int it = 0; it < 8; ++it) {
      int rl = it * 4 + (lane >> 4);
      int cl = 4 * c0;
      if (cl < jn * 16) {
        f32x4 v = *(const f32x4*)&xp[rl * 64 + (cl ^ (((rl >> 2) & 3) << 4))];
        int row = mt0 * 16 + rl;
        __builtin_nontemporal_store(v, (f32x4*)(out + (size_t)row * NCOLS + colbase + cl));
      }
    }
  }
}

// ---------------------------------------------------------------- launcher

extern "C" void kernel_launch(void* const* d_in, const int* in_sizes, int n_in,
                              void* d_out, int out_size, void* d_ws, size_t ws_size,
                              hipStream_t stream) {
  const int*   x      = (const int*)d_in[0];
  const int*   ei     = (const int*)d_in[1];
  const int*   batch  = (const int*)d_in[2];
  const float* emb    = (const float*)d_in[4];
  const float* conv_w = (const float*)d_in[5];
  const float* w_ih   = (const float*)d_in[6];
  const float* w_hh   = (const float*)d_in[7];
  const float* b_ih   = (const float*)d_in[8];
  const float* b_hh   = (const float*)d_in[9];
  const float* q_w    = (const float*)d_in[10];
  const float* q_b    = (const float*)d_in[11];
  const float* w2     = (const float*)d_in[12];
  const float* b2     = (const float*)d_in[13];
  const float* w3     = (const float*)d_in[14];
  const float* b3     = (const float*)d_in[15];
  const float* w4     = (const float*)d_in[16];
  const float* b4     = (const float*)d_in[17];

  const int N = in_sizes[0];            // 49152
  const int E = in_sizes[1] / 2;        // 98304
  const int NNODE = in_sizes[4] / DDIM; // 50000
  const int B = out_size / NNODE;       // 4096

  size_t ND = (size_t)N * DDIM;
  float* ws   = (float*)d_ws;
  float* h0   = ws;            // [N,100]
  float* aggH = ws + ND;       // [N,100]
  float* xh   = ws + 2 * ND;   // [N,100]
  float* t2   = ws + 3 * ND;   // [N,100]
  float* aux  = ws + 4 * ND;
  float* t3v  = aux;                           // [B,100]
  float* Scat = t3v + (size_t)B * DDIM;        // [B,300]
  int*   lastI = (int*)(Scat + 3 * (size_t)B * DDIM); // [B]

  const int MT = (B + 15) / 16;          // 256
  const int NT = (NNODE + 15) / 16;      // 3125
  short8* Whi = (short8*)(lastI + B);    // 8 sets x [7][4][64]
  short8* Ahi = Whi + 8 * 7 * 4 * 64;
  short8* Alo = Ahi + (size_t)MT * 4 * 64;
  short8* Bhi = Alo + (size_t)MT * 4 * 64;
  short8* Blo = Bhi + (size_t)NT * 4 * 64;

  dim3 blk(256);
  const int nblkA = N / 128;   // 384
  const int nblkB = B / 128;   // 32

  int packTotal = NT * 4 * 64 + 8 * 7 * 4 * 64;
  k_packAll<<<(packTotal + 255) / 256, blk, 0, stream>>>(
      emb, w_ih, conv_w, w_hh, w2, w3, Bhi, Blo, Whi, NNODE, NT);
  k_gather4<<<(N * 25 + 255) / 256, blk, 0, stream>>>(x, emb, (float4*)h0, (float4*)aggH,
                                                      batch, lastI, N);
  k_scatter<<<(E * 25 + 255) / 256, blk, 0, stream>>>(ei, h0, aggH, E);
  k_grufused<<<nblkA, blk, 0, stream>>>(aggH, h0, Whi, b_ih, b_hh, xh);
  k_mm100t3<<<nblkA + nblkB, blk, 0, stream>>>(xh, Whi, b2, b3, lastI, t2, t3v, nblkA);
  k_session<<<(B + 3) / 4, blk, 0, stream>>>(xh, t2, t3v, q_w, q_b, lastI, Scat, B);
  k_gemmS<<<dim3(2, B / 128), blk, 0, stream>>>(Scat, w4, b4, (short*)Ahi, (short*)Alo, B);

  const int NTCHUNK = 48;                          // multiple of NTG
  const int NCHUNKS = (NT + NTCHUNK - 1) / NTCHUNK; // 66
  k_bigmm<<<dim3(nblkB, NCHUNKS), blk, 0, stream>>>(
      Ahi, Alo, Bhi, Blo, (float*)d_out, NT, NTCHUNK, NNODE);
}

// Round 7
// 507.883 us; speedup vs baseline: 2.6497x; 1.0072x over previous
//
#include <hip/hip_runtime.h>
#include <math.h>

#define DDIM 100   // embed dim
#define PFD  4     // k_bigmm LDS ring depth
#define NTG  4     // k_bigmm n-tiles per store group (64 cols -> 256B/row stores)

using short8 = __attribute__((ext_vector_type(8))) short;
using f32x4  = __attribute__((ext_vector_type(4))) float;

// ---------------------------------------------------------------- utilities

__device__ __forceinline__ float sigm(float x) { return 1.f / (1.f + expf(-x)); }

__device__ __forceinline__ f32x4 mfma16(short8 a, short8 b, f32x4 c) {
  return __builtin_amdgcn_mfma_f32_16x16x32_bf16(a, b, c, 0, 0, 0);
}

__device__ __forceinline__ void gld_lds16(const void* g, void* l) {
  __builtin_amdgcn_global_load_lds(
      (const __attribute__((address_space(1))) void*)g,
      (__attribute__((address_space(3))) void*)l, 16, 0, 0);
}

// RNE bf16 split: v ~= hi + lo
__device__ __forceinline__ void bf16split(float v, short& h, short& l) {
  unsigned u = __float_as_uint(v);
  unsigned hb = (u + 0x7fffu + ((u >> 16) & 1u)) & 0xffff0000u;
  float res = v - __uint_as_float(hb);
  unsigned u2 = __float_as_uint(res);
  h = (short)(hb >> 16);
  l = (short)((u2 + 0x7fffu + ((u2 >> 16) & 1u)) >> 16);
}

__device__ __forceinline__ short bf16hi(float v) {
  unsigned u = __float_as_uint(v);
  return (short)((u + 0x7fffu + ((u >> 16) & 1u)) >> 16);
}

// ---------------------------------------------------------------- elementwise

// h0 = emb[x-1], last-node-per-session (aggH init handled by k_aggregate)
__global__ void k_gather4(const int* __restrict__ x, const float* __restrict__ emb,
                          float4* __restrict__ h0,
                          const int* __restrict__ batch, int* __restrict__ last_idx,
                          int n) {
  int i = blockIdx.x * 256 + threadIdx.x;
  if (i < n * 25) {
    int node = i / 25, c = i - node * 25;
    h0[i] = *(const float4*)(emb + (size_t)(x[node] - 1) * DDIM + 4 * c);
  }
  if (i < n) {
    if (i == n - 1 || batch[i + 1] != batch[i]) last_idx[batch[i]] = i;
  }
}

// ---------------------------------------------------------------- aggregation
// aggH[d] = sum over edges (s->d) of h0[s], WITHOUT global atomics.
// Block owns 256 dst rows in LDS; scans dst array (broadcast read, L2/L3);
// ballot-compacts matches; 25 lanes cooperatively accumulate each edge row.
__global__ __launch_bounds__(256, 1) void k_aggregate(
    const int* __restrict__ ei, const float* __restrict__ h0,
    float* __restrict__ aggH, int E) {
  __shared__ float acc[256 * DDIM];  // 100 KB
  const int tid = threadIdx.x;
  const int lane = tid & 63;
  const int wave = tid >> 6;
  const int r0 = blockIdx.x * 256;

  for (int idx = tid; idx < 256 * DDIM / 4; idx += 256)
    ((float4*)acc)[idx] = make_float4(0.f, 0.f, 0.f, 0.f);
  __syncthreads();

  const int quarter = E >> 2;            // E = 98304 -> 24576, multiple of 64
  const int base = wave * quarter;
  for (int it = 0; it < quarter; it += 64) {
    int e = base + it + lane;
    int d = ei[E + e] - r0;
    bool match = (unsigned)d < 256u;
    int src = match ? ei[e] : 0;
    unsigned long long mask = __ballot(match);
    while (mask) {
      int bit = __ffsll(mask) - 1;
      mask &= mask - 1;
      int ds = __shfl(d, bit, 64);
      int ss = __shfl(src, bit, 64);
      if (lane < 25) {
        float4 v = *(const float4*)(h0 + (size_t)ss * DDIM + 4 * lane);
        float* a = acc + ds * DDIM + 4 * lane;
        atomicAdd(a + 0, v.x); atomicAdd(a + 1, v.y);
        atomicAdd(a + 2, v.z); atomicAdd(a + 3, v.w);
      }
    }
  }
  __syncthreads();
  float4* of = (float4*)(aggH + (size_t)r0 * DDIM);
  for (int idx = tid; idx < 256 * DDIM / 4; idx += 256)
    of[idx] = ((const float4*)acc)[idx];
}

// ---------------------------------------------------------------- session pooling
// one wave per session; 4 nodes/iteration via 16-lane groups, each group an
// independent online-softmax stream; merged across groups at the end.
__global__ __launch_bounds__(256) void k_session(
    const float* __restrict__ xh, const float* __restrict__ t2,
    const float* __restrict__ t3v,
    const float* __restrict__ q_w, const float* __restrict__ q_b,
    const int* __restrict__ last_idx, float* __restrict__ Scat, int B) {
  int sid = blockIdx.x * 4 + (threadIdx.x >> 6);
  if (sid >= B) return;
  const int lane = threadIdx.x & 63;
  const int g = lane >> 4;
  const int s = lane & 15;
  const int start = (sid == 0) ? 0 : last_idx[sid - 1] + 1;
  const int end = last_idx[sid];

  float vr[7], t3r[7], qr[7];
#pragma unroll
  for (int k = 0; k < 7; ++k) {
    int c = s + 16 * k;
    bool ok = c < DDIM;
    vr[k]  = ok ? xh[(size_t)end * DDIM + c] : 0.f;
    t3r[k] = ok ? t3v[(size_t)sid * DDIM + c] : 0.f;
    qr[k]  = ok ? q_w[c] : 0.f;
  }
  const float qb = q_b[0];

  float m = -INFINITY, den = 0.f;
  float ss[7] = {}, sg[7] = {};
  for (int i = start; i <= end; i += 4) {
    int ni = i + g;
    bool act = ni <= end;
    int nrow = act ? ni : end;
    float xv[7];
    float l = 0.f, ga = 0.f;
#pragma unroll
    for (int k = 0; k < 7; ++k) {
      int c = s + 16 * k;
      float x = (c < DDIM) ? xh[(size_t)nrow * DDIM + c] : 0.f;
      float tv = (c < DDIM) ? t2[(size_t)nrow * DDIM + c] : 0.f;
      xv[k] = x;
      l = fmaf(x, vr[k], l);
      ga = fmaf(qr[k], sigm(tv + t3r[k]), ga);
    }
#pragma unroll
    for (int o = 1; o <= 8; o <<= 1) {
      l += __shfl_xor(l, o, 64);
      ga += __shfl_xor(ga, o, 64);
    }
    float ls = act ? l : -INFINITY;
    float alpha = act ? (ga + qb) : 0.f;
    float mn = fmaxf(m, ls);
    float cf = (m == -INFINITY) ? 0.f : expf(m - mn);
    float p = act ? expf(ls - mn) : 0.f;
    den = den * cf + p;
#pragma unroll
    for (int k = 0; k < 7; ++k) {
      ss[k] = ss[k] * cf + p * xv[k];
      sg[k] = fmaf(alpha, xv[k], sg[k]);
    }
    m = mn;
  }
  // merge 4 group streams
  float mAll = m;
  mAll = fmaxf(mAll, __shfl_xor(mAll, 16, 64));
  mAll = fmaxf(mAll, __shfl_xor(mAll, 32, 64));
  float sc = (m == -INFINITY) ? 0.f : expf(m - mAll);
  float dv = den * sc;
  dv += __shfl_xor(dv, 16, 64);
  dv += __shfl_xor(dv, 32, 64);
  float inv = 1.f / dv;
  float* Sc = Scat + (size_t)sid * 300;
#pragma unroll
  for (int k = 0; k < 7; ++k) {
    float sv = ss[k] * sc;
    float gv = sg[k];
    sv += __shfl_xor(sv, 16, 64);  sv += __shfl_xor(sv, 32, 64);
    gv += __shfl_xor(gv, 16, 64);  gv += __shfl_xor(gv, 32, 64);
    int c = s + 16 * k;
    if (g == 0 && c < DDIM) {
      Sc[c] = sv * inv;
      Sc[100 + c] = gv;
      Sc[200 + c] = vr[k];
    }
  }
}

// ---------------------------------------------------------------- combined pack
__global__ void k_packAll(const float* __restrict__ emb,
                          const float* __restrict__ w_ih, const float* __restrict__ conv_w,
                          const float* __restrict__ w_hh, const float* __restrict__ w2,
                          const float* __restrict__ w3,
                          short8* __restrict__ Bhi, short8* __restrict__ Blo,
                          short8* __restrict__ Whi, int NNODE, int NT) {
  int gid = blockIdx.x * 256 + threadIdx.x;
  int embN = NT * 4 * 64;
  if (gid < embN) {
    int lane = gid & 63;
    int kt = (gid >> 6) & 3;
    int rt = gid >> 8;
    int r = rt * 16 + (lane & 15);
    if (r >= NNODE) r = NNODE - 1;
    int kb = kt * 32 + (lane >> 4) * 8;
    short8 h, l;
#pragma unroll
    for (int j = 0; j < 8; ++j) {
      int k = kb + j;
      float v = (k < DDIM) ? emb[(size_t)r * DDIM + k] : 0.f;
      short hh, ll;
      bf16split(v, hh, ll);
      h[j] = hh; l[j] = ll;
    }
    Bhi[gid] = h;
    Blo[gid] = l;
  } else {
    int wg = gid - embN;
    if (wg >= 8 * 7 * 4 * 64) return;
    int lane = wg & 63;
    int kt = (wg >> 6) & 3;
    int snt = wg >> 8;
    int nt = snt % 7;
    int s = snt / 7;
    int d = nt * 16 + (lane & 15);
    int k0 = kt * 32 + (lane >> 4) * 8;
    short8 h;
#pragma unroll
    for (int j = 0; j < 8; ++j) {
      int k = k0 + j;
      float v = 0.f;
      if (d < 100 && k < 100) {
        if (s < 3) {
          const float* wr = w_ih + (size_t)(s * 100 + d) * 100;
          const float* cr = conv_w + (size_t)k * 100;
          float acc = 0.f;
          for (int t = 0; t < 100; ++t) acc = fmaf(wr[t], cr[t], acc);
          v = acc;
        } else if (s < 6) {
          v = w_hh[(size_t)((s - 3) * 100 + d) * 100 + k];
        } else if (s == 6) {
          v = w2[(size_t)d * 100 + k];
        } else {
          v = w3[(size_t)d * 100 + k];
        }
      }
      h[j] = bf16hi(v);
    }
    Whi[wg] = h;
  }
}

// hi-only A fragment loads for one 16-row m-tile (K=100 padded to 128)
__device__ __forceinline__ void load_afragsH(const float* __restrict__ A, int rowBase,
                                             int lane, short8 ah[4]) {
  int r = rowBase + (lane & 15);
  int g = lane >> 4;
#pragma unroll
  for (int kt = 0; kt < 4; ++kt) {
    int k0 = kt * 32 + g * 8;
    float4 f0 = make_float4(0.f, 0.f, 0.f, 0.f);
    float4 f1 = make_float4(0.f, 0.f, 0.f, 0.f);
    if (k0 < 100)     f0 = *(const float4*)(A + (size_t)r * DDIM + k0);
    if (k0 + 4 < 100) f1 = *(const float4*)(A + (size_t)r * DDIM + k0 + 4);
    short8 h;
    h[0] = bf16hi(f0.x); h[1] = bf16hi(f0.y); h[2] = bf16hi(f0.z); h[3] = bf16hi(f0.w);
    h[4] = bf16hi(f1.x); h[5] = bf16hi(f1.y); h[6] = bf16hi(f1.z); h[7] = bf16hi(f1.w);
    ah[kt] = h;
  }
}

__device__ __forceinline__ void load_afragsHg(const float* __restrict__ A,
                                              const int* __restrict__ idx, int base,
                                              int lane, short8 ah[4]) {
  int r = idx[base + (lane & 15)];
  int g = lane >> 4;
#pragma unroll
  for (int kt = 0; kt < 4; ++kt) {
    int k0 = kt * 32 + g * 8;
    float4 f0 = make_float4(0.f, 0.f, 0.f, 0.f);
    float4 f1 = make_float4(0.f, 0.f, 0.f, 0.f);
    if (k0 < 100)     f0 = *(const float4*)(A + (size_t)r * DDIM + k0);
    if (k0 + 4 < 100) f1 = *(const float4*)(A + (size_t)r * DDIM + k0 + 4);
    short8 h;
    h[0] = bf16hi(f0.x); h[1] = bf16hi(f0.y); h[2] = bf16hi(f0.z); h[3] = bf16hi(f0.w);
    h[4] = bf16hi(f1.x); h[5] = bf16hi(f1.y); h[6] = bf16hi(f1.z); h[7] = bf16hi(f1.w);
    ah[kt] = h;
  }
}

// ---------------------------------------------------------------- fused GGC+GRU
__global__ __launch_bounds__(256) void k_grufused(
    const float* __restrict__ aggH, const float* __restrict__ h0,
    const short8* __restrict__ Whi,
    const float* __restrict__ b_ih, const float* __restrict__ b_hh,
    float* __restrict__ xh) {
  const int lane = threadIdx.x & 63;
  const int wave = threadIdx.x >> 6;
  const int rowBase = blockIdx.x * 128 + wave * 32;
  short8 aI0[4], aI1[4], aH0[4], aH1[4];
  load_afragsH(aggH, rowBase, lane, aI0);
  load_afragsH(aggH, rowBase + 16, lane, aI1);
  load_afragsH(h0, rowBase, lane, aH0);
  load_afragsH(h0, rowBase + 16, lane, aH1);
  const int c0 = lane & 15;
  const int r0 = (lane >> 4) * 4;

  for (int nt = 0; nt < 7; ++nt) {
    int d = nt * 16 + c0;
    f32x4 a0[6] = {};
    f32x4 a1[6] = {};
#pragma unroll
    for (int s = 0; s < 6; ++s) {
#pragma unroll
      for (int kt = 0; kt < 4; ++kt) {
        short8 w = Whi[(((size_t)s * 7 + nt) * 4 + kt) * 64 + lane];
        if (s < 3) {
          a0[s] = mfma16(aI0[kt], w, a0[s]);
          a1[s] = mfma16(aI1[kt], w, a1[s]);
        } else {
          a0[s] = mfma16(aH0[kt], w, a0[s]);
          a1[s] = mfma16(aH1[kt], w, a1[s]);
        }
      }
    }
    if (d < 100) {
      float bir = b_ih[d], biz = b_ih[100 + d], bin_ = b_ih[200 + d];
      float bhr = b_hh[d], bhz = b_hh[100 + d], bhn = b_hh[200 + d];
#pragma unroll
      for (int ri = 0; ri < 4; ++ri) {
        {
          int row = rowBase + r0 + ri;
          float r = sigm(a0[0][ri] + bir + a0[3][ri] + bhr);
          float z = sigm(a0[1][ri] + biz + a0[4][ri] + bhz);
          float n = tanhf(a0[2][ri] + bin_ + r * (a0[5][ri] + bhn));
          float h0v = h0[(size_t)row * DDIM + d];
          float v = (1.f - z) * n + z * h0v;
          xh[(size_t)row * DDIM + d] = v > 0.f ? v : 0.f;
        }
        {
          int row = rowBase + 16 + r0 + ri;
          float r = sigm(a1[0][ri] + bir + a1[3][ri] + bhr);
          float z = sigm(a1[1][ri] + biz + a1[4][ri] + bhz);
          float n = tanhf(a1[2][ri] + bin_ + r * (a1[5][ri] + bhn));
          float h0v = h0[(size_t)row * DDIM + d];
          float v = (1.f - z) * n + z * h0v;
          xh[(size_t)row * DDIM + d] = v > 0.f ? v : 0.f;
        }
      }
    }
  }
}

// t2 = xh @ w2^T + b2 (blocks < nblkA) ; t3v = xh[lastI] @ w3^T + b3 (rest)
__global__ __launch_bounds__(256) void k_mm100t3(
    const float* __restrict__ xh, const short8* __restrict__ Whi,
    const float* __restrict__ b2, const float* __restrict__ b3,
    const int* __restrict__ lastI,
    float* __restrict__ t2, float* __restrict__ t3v, int nblkA) {
  const int bb = blockIdx.x;
  const int lane = threadIdx.x & 63;
  const int wave = threadIdx.x >> 6;
  const bool isT3 = bb >= nblkA;
  const int setIdx = isT3 ? 7 : 6;
  const float* bias = isT3 ? b3 : b2;
  float* out = isT3 ? t3v : t2;
  const int rowBase = (isT3 ? (bb - nblkA) : bb) * 128 + wave * 32;

  short8 a0[4], a1[4];
  if (isT3) {
    load_afragsHg(xh, lastI, rowBase, lane, a0);
    load_afragsHg(xh, lastI, rowBase + 16, lane, a1);
  } else {
    load_afragsH(xh, rowBase, lane, a0);
    load_afragsH(xh, rowBase + 16, lane, a1);
  }
  const int c0 = lane & 15;
  const int r0 = (lane >> 4) * 4;

  for (int nt = 0; nt < 7; ++nt) {
    int d = nt * 16 + c0;
    f32x4 ac0 = {0.f, 0.f, 0.f, 0.f};
    f32x4 ac1 = {0.f, 0.f, 0.f, 0.f};
#pragma unroll
    for (int kt = 0; kt < 4; ++kt) {
      short8 w = Whi[(((size_t)setIdx * 7 + nt) * 4 + kt) * 64 + lane];
      ac0 = mfma16(a0[kt], w, ac0);
      ac1 = mfma16(a1[kt], w, ac1);
    }
    if (d < 100) {
      float b = bias[d];
#pragma unroll
      for (int ri = 0; ri < 4; ++ri) {
        out[(size_t)(rowBase + r0 + ri) * DDIM + d] = ac0[ri] + b;
        out[(size_t)(rowBase + 16 + r0 + ri) * DDIM + d] = ac1[ri] + b;
      }
    }
  }
}

// ---------------------------------------------------------------- S GEMM -> packed frags
__global__ __launch_bounds__(256, 2) void k_gemmS(
    const float* __restrict__ A, const float* __restrict__ Bm,
    const float* __restrict__ bias, short* __restrict__ Ph, short* __restrict__ Pl,
    int M) {
  __shared__ float4 As4[25 * 128];
  __shared__ float4 Bs4[25 * 64];
  const int m0 = blockIdx.y * 128;
  const int n0 = blockIdx.x * 64;
  const int t = threadIdx.x;
  const int tx = t & 15;
  const int ty = t >> 4;
  float acc[8][4] = {};

  for (int kt = 0; kt < 300; kt += 100) {
    for (int idx = t; idx < 128 * 25; idx += 256) {
      int r = idx / 25, k4 = idx - r * 25;
      int ar = m0 + r; if (ar >= M) ar = M - 1;
      float4 v = *(const float4*)(A + (size_t)ar * 300 + kt + 4 * k4);
      As4[k4 * 128 + (r ^ (k4 & 7))] = v;
    }
    for (int idx = t; idx < 64 * 25; idx += 256) {
      int r = idx / 25, k4 = idx - r * 25;
      int br = n0 + r;
      float4 v = make_float4(0.f, 0.f, 0.f, 0.f);
      if (br < 100) v = *(const float4*)(Bm + (size_t)br * 300 + kt + 4 * k4);
      Bs4[k4 * 64 + (r ^ (k4 & 7))] = v;
    }
    __syncthreads();
#pragma unroll 5
    for (int k4 = 0; k4 < 25; ++k4) {
      const int s = k4 & 7;
      float4 av[8], bv[4];
#pragma unroll
      for (int i = 0; i < 8; ++i) av[i] = As4[k4 * 128 + ((ty + 16 * i) ^ s)];
#pragma unroll
      for (int j = 0; j < 4; ++j) bv[j] = Bs4[k4 * 64 + ((tx + 16 * j) ^ s)];
#pragma unroll
      for (int i = 0; i < 8; ++i) {
#pragma unroll
        for (int j = 0; j < 4; ++j) {
          acc[i][j] = fmaf(av[i].x, bv[j].x, acc[i][j]);
          acc[i][j] = fmaf(av[i].y, bv[j].y, acc[i][j]);
          acc[i][j] = fmaf(av[i].z, bv[j].z, acc[i][j]);
          acc[i][j] = fmaf(av[i].w, bv[j].w, acc[i][j]);
        }
      }
    }
    __syncthreads();
  }

#pragma unroll
  for (int i = 0; i < 8; ++i) {
    int row = m0 + ty + 16 * i;
    if (row >= M) continue;
#pragma unroll
    for (int j = 0; j < 4; ++j) {
      int col = n0 + tx + 16 * j;   // 0..127 (>=100 -> zero pad slot)
      float v = (col < 100) ? (acc[i][j] + bias[col]) : 0.f;
      short hh, ll;
      bf16split(v, hh, ll);
      int rt = row >> 4, kt = col >> 5;
      int lane_t = (row & 15) + 16 * ((col >> 3) & 3);
      size_t base = ((((size_t)rt * 4 + kt) * 64 + lane_t) << 3) + (col & 7);
      Ph[base] = hh;
      Pl[base] = ll;
    }
  }
}

// ---------------------------------------------------------------- big MFMA GEMM
__global__ __launch_bounds__(256) void k_bigmm(
    const short8* __restrict__ Ahi, const short8* __restrict__ Alo,
    const short8* __restrict__ Bhi, const short8* __restrict__ Blo,
    float* __restrict__ out, int NT, int NTCHUNK, int NCOLS) {
  __shared__ short8 Bs[PFD * 8 * 64];   // 32 KB ring
  __shared__ float Xp[4 * 32 * 64];     // 32 KB transpose stripes (8KB/wave)
  const int lane = threadIdx.x & 63;
  const int wave = threadIdx.x >> 6;
  const int mt0 = blockIdx.x * 8 + wave * 2;

  short8 ah[2][4], al[2][4];
#pragma unroll
  for (int mi = 0; mi < 2; ++mi)
#pragma unroll
    for (int kt = 0; kt < 4; ++kt) {
      size_t off = ((size_t)(mt0 + mi) * 4 + kt) * 64 + lane;
      ah[mi][kt] = Ahi[off];
      al[mi][kt] = Alo[off];
    }

  const int nt0 = blockIdx.y * NTCHUNK;
  const int nt1 = min(NT, nt0 + NTCHUNK);
  const int r0 = (lane >> 4) * 4;
  const int c0 = lane & 15;
  float* xp = &Xp[wave * 32 * 64];

  auto issueB = [&](int nt) {
    int s = nt & (PFD - 1);
    gld_lds16(Bhi + ((size_t)nt * 4 + wave) * 64 + lane, &Bs[(s * 8 + wave) * 64]);
    gld_lds16(Blo + ((size_t)nt * 4 + wave) * 64 + lane, &Bs[(s * 8 + 4 + wave) * 64]);
  };

  for (int i = 0; i < PFD && nt0 + i < nt1; ++i) issueB(nt0 + i);
  asm volatile("s_waitcnt vmcnt(6)" ::: "memory");
  __builtin_amdgcn_s_barrier();

  for (int g = nt0; g < nt1; g += NTG) {
    const int jn = min(NTG, nt1 - g);
    f32x4 acc[2][NTG] = {};
#pragma unroll
    for (int j = 0; j < NTG; ++j) {
      if (j >= jn) break;
      const int nt = g + j;
      const int s = nt & (PFD - 1);
      short8 bh[4], bl[4];
#pragma unroll
      for (int kt = 0; kt < 4; ++kt) {
        bh[kt] = Bs[(s * 8 + kt) * 64 + lane];
        bl[kt] = Bs[(s * 8 + 4 + kt) * 64 + lane];
      }
      asm volatile("s_waitcnt lgkmcnt(0)" ::: "memory");
      __builtin_amdgcn_s_barrier();
      if (nt + PFD < nt1) issueB(nt + PFD);
      __builtin_amdgcn_sched_barrier(0);
#pragma unroll
      for (int kt = 0; kt < 4; ++kt) {
        acc[0][j] = mfma16(ah[0][kt], bh[kt], acc[0][j]);
        acc[1][j] = mfma16(ah[1][kt], bh[kt], acc[1][j]);
        acc[0][j] = mfma16(ah[0][kt], bl[kt], acc[0][j]);
        acc[1][j] = mfma16(ah[1][kt], bl[kt], acc[1][j]);
        acc[0][j] = mfma16(al[0][kt], bh[kt], acc[0][j]);
        acc[1][j] = mfma16(al[1][kt], bh[kt], acc[1][j]);
      }
      asm volatile("s_waitcnt vmcnt(14)" ::: "memory");
      __builtin_amdgcn_s_barrier();
    }
#pragma unroll
    for (int mi = 0; mi < 2; ++mi)
#pragma unroll
      for (int j = 0; j < NTG; ++j) {
        if (j < jn) {
#pragma unroll
          for (int r = 0; r < 4; ++r) {
            int rl = mi * 16 + r0 + r;
            int cl = j * 16 + c0;
            xp[rl * 64 + (cl ^ (((rl >> 2) & 3) << 4))] = acc[mi][j][r];
          }
        }
      }
    const int colbase = g * 16;
#pragma unroll
    for (int it = 0; it < 8; ++it) {
      int rl = it * 4 + (lane >> 4);
      int cl = 4 * c0;
      if (cl < jn * 16) {
        f32x4 v = *(const f32x4*)&xp[rl * 64 + (cl ^ (((rl >> 2) & 3) << 4))];
        int row = mt0 * 16 + rl;
        __builtin_nontemporal_store(v, (f32x4*)(out + (size_t)row * NCOLS + colbase + cl));
      }
    }
  }
}

// ---------------------------------------------------------------- launcher

extern "C" void kernel_launch(void* const* d_in, const int* in_sizes, int n_in,
                              void* d_out, int out_size, void* d_ws, size_t ws_size,
                              hipStream_t stream) {
  const int*   x      = (const int*)d_in[0];
  const int*   ei     = (const int*)d_in[1];
  const int*   batch  = (const int*)d_in[2];
  const float* emb    = (const float*)d_in[4];
  const float* conv_w = (const float*)d_in[5];
  const float* w_ih   = (const float*)d_in[6];
  const float* w_hh   = (const float*)d_in[7];
  const float* b_ih   = (const float*)d_in[8];
  const float* b_hh   = (const float*)d_in[9];
  const float* q_w    = (const float*)d_in[10];
  const float* q_b    = (const float*)d_in[11];
  const float* w2     = (const float*)d_in[12];
  const float* b2     = (const float*)d_in[13];
  const float* w3     = (const float*)d_in[14];
  const float* b3     = (const float*)d_in[15];
  const float* w4     = (const float*)d_in[16];
  const float* b4     = (const float*)d_in[17];

  const int N = in_sizes[0];            // 49152
  const int E = in_sizes[1] / 2;        // 98304
  const int NNODE = in_sizes[4] / DDIM; // 50000
  const int B = out_size / NNODE;       // 4096

  size_t ND = (size_t)N * DDIM;
  float* ws   = (float*)d_ws;
  float* h0   = ws;            // [N,100]
  float* aggH = ws + ND;       // [N,100]
  float* xh   = ws + 2 * ND;   // [N,100]
  float* t2   = ws + 3 * ND;   // [N,100]
  float* aux  = ws + 4 * ND;
  float* t3v  = aux;                           // [B,100]
  float* Scat = t3v + (size_t)B * DDIM;        // [B,300]
  int*   lastI = (int*)(Scat + 3 * (size_t)B * DDIM); // [B]

  const int MT = (B + 15) / 16;          // 256
  const int NT = (NNODE + 15) / 16;      // 3125
  short8* Whi = (short8*)(lastI + B);    // 8 sets x [7][4][64]
  short8* Ahi = Whi + 8 * 7 * 4 * 64;
  short8* Alo = Ahi + (size_t)MT * 4 * 64;
  short8* Bhi = Alo + (size_t)MT * 4 * 64;
  short8* Blo = Bhi + (size_t)NT * 4 * 64;

  dim3 blk(256);
  const int nblkA = N / 128;   // 384
  const int nblkB = B / 128;   // 32

  int packTotal = NT * 4 * 64 + 8 * 7 * 4 * 64;
  k_packAll<<<(packTotal + 255) / 256, blk, 0, stream>>>(
      emb, w_ih, conv_w, w_hh, w2, w3, Bhi, Blo, Whi, NNODE, NT);
  k_gather4<<<(N * 25 + 255) / 256, blk, 0, stream>>>(x, emb, (float4*)h0, batch, lastI, N);
  k_aggregate<<<N / 256, blk, 0, stream>>>(ei, h0, aggH, E);
  k_grufused<<<nblkA, blk, 0, stream>>>(aggH, h0, Whi, b_ih, b_hh, xh);
  k_mm100t3<<<nblkA + nblkB, blk, 0, stream>>>(xh, Whi, b2, b3, lastI, t2, t3v, nblkA);
  k_session<<<(B + 3) / 4, blk, 0, stream>>>(xh, t2, t3v, q_w, q_b, lastI, Scat, B);
  k_gemmS<<<dim3(2, B / 128), blk, 0, stream>>>(Scat, w4, b4, (short*)Ahi, (short*)Alo, B);

  const int NTCHUNK = 48;                           // multiple of NTG
  const int NCHUNKS = (NT + NTCHUNK - 1) / NTCHUNK; // 66
  k_bigmm<<<dim3(nblkB, NCHUNKS), blk, 0, stream>>>(
      Ahi, Alo, Bhi, Blo, (float*)d_out, NT, NTCHUNK, NNODE);
}